// Round 3
// baseline (745.224 us; speedup 1.0000x reference)
//
#include <hip/hip_runtime.h>
#include <hip/hip_bf16.h>

// GNN pipeline: 2x GraphConv(norm=both, edge_weight) + LeakyReLU + GraphNorm,
// segment-mean readout, 3x (Linear+LeakyReLU+InstanceNorm), classifier.
// Restructurings:
//  - conv2: W2 applied BEFORE scatter (linearity) -> scatter at F=64 not 128
//  - GraphNorm reduced to per-feature affine (a,b) from column sums/sumsq
//  - h2 never materialized: only global stats + per-graph segment sums
#define NEG_SLOPE 0.01f
#define EPS 1e-5f

__device__ __forceinline__ float leaky(float x){ return x > 0.f ? x : NEG_SLOPE * x; }

// ---- degrees ----
__global__ void deg_kernel(const int* __restrict__ src, const int* __restrict__ dst,
                           float* __restrict__ dout, float* __restrict__ din, int E){
  int e = blockIdx.x * blockDim.x + threadIdx.x;
  if (e < E){
    atomicAdd(&dout[src[e]], 1.f);
    atomicAdd(&din[dst[e]], 1.f);
  }
}

__global__ void norm_kernel(float* __restrict__ dout, float* __restrict__ din, int N){
  int i = blockIdx.x * blockDim.x + threadIdx.x;
  if (i < N){
    float a = dout[i]; dout[i] = rsqrtf(a > 0.f ? a : 1.f);
    float b = din[i];  din[i]  = rsqrtf(b > 0.f ? b : 1.f);
  }
}

// ---- edge aggregation: agg[dst][f] += x[src][f] * ew * (opt out_n[src]) ----
// one wave (64 lanes) per edge; lane = feature. Gather is one 256B row.
template<bool USE_OUTN>
__global__ void edge_agg(const float* __restrict__ x, const int* __restrict__ src,
                         const int* __restrict__ dst, const float* __restrict__ ew,
                         const float* __restrict__ out_n, float* __restrict__ agg, int E){
  int wave = (blockIdx.x * blockDim.x + threadIdx.x) >> 6;
  int f = threadIdx.x & 63;
  if (wave >= E) return;
  int s = src[wave], d = dst[wave];
  float w = ew[wave];
  if (USE_OUTN) w *= out_n[s];
  float val = x[(size_t)s * 64 + f] * w;
  atomicAdd(&agg[(size_t)d * 64 + f], val);
}

// ---- h1 = leaky((agg1 * in_n) @ W1)  [Nx64]@[64x128] ----
__global__ __launch_bounds__(256) void gemm1_kernel(const float* __restrict__ agg,
    const float* __restrict__ in_n, const float* __restrict__ W1,
    float* __restrict__ h1, int N){
  __shared__ float sW[64 * 128];
  __shared__ float sIn[8][64];
  int t = threadIdx.x;
  for (int i = t; i < 64 * 128; i += 256) sW[i] = W1[i];
  int r0 = blockIdx.x * 8;
  for (int i = t; i < 8 * 64; i += 256){
    int ir = i >> 6, k = i & 63;
    int row = r0 + ir;
    sIn[ir][k] = (row < N) ? agg[(size_t)row * 64 + k] * in_n[row] : 0.f;
  }
  __syncthreads();
  int c = t & 127;
  int ib = t >> 7;            // 0..1
  float acc[4] = {0.f, 0.f, 0.f, 0.f};
  for (int k = 0; k < 64; ++k){
    float w = sW[k * 128 + c];
    acc[0] += sIn[ib + 0][k] * w;
    acc[1] += sIn[ib + 2][k] * w;
    acc[2] += sIn[ib + 4][k] * w;
    acc[3] += sIn[ib + 6][k] * w;
  }
  for (int j = 0; j < 4; ++j){
    int row = r0 + ib + 2 * j;
    if (row < N) h1[(size_t)row * 128 + c] = leaky(acc[j]);
  }
}

// ---- per-feature column sums / sums-of-squares ----
template<int F>
__global__ void colstats_kernel(const float* __restrict__ h, int N,
                                float* __restrict__ sum, float* __restrict__ sumsq){
  int f = threadIdx.x;            // blockDim.x == F
  float s = 0.f, s2 = 0.f;
  for (int r = blockIdx.x; r < N; r += gridDim.x){
    float v = h[(size_t)r * F + f];
    s += v; s2 += v * v;
  }
  atomicAdd(&sum[f], s);
  atomicAdd(&sumsq[f], s2);
}

// ---- GraphNorm -> affine: a = g*rsqrt(var+eps), b = beta - a*alpha*mean ----
__global__ void finalize_norm(const float* __restrict__ sum, const float* __restrict__ sumsq,
                              const float* __restrict__ gamma, const float* __restrict__ beta,
                              const float* __restrict__ alpha,
                              float* __restrict__ a, float* __restrict__ b, int F, float invN){
  int f = threadIdx.x;
  if (f < F){
    float m = sum[f] * invN;
    float ex2 = sumsq[f] * invN;
    float al = alpha[f];
    float var = ex2 - m * m * al * (2.f - al);
    float av = gamma[f] * rsqrtf(var + EPS);
    a[f] = av;
    b[f] = beta[f] - av * al * m;
  }
}

// ---- z = ((a1*h1 + b1) * out_n) @ W2   [Nx128]@[128x64] ----
__global__ __launch_bounds__(256) void gemm2_kernel(const float* __restrict__ h1,
    const float* __restrict__ out_n, const float* __restrict__ a1, const float* __restrict__ b1,
    const float* __restrict__ W2, float* __restrict__ z, int N){
  __shared__ float sW[128 * 64];
  __shared__ float sIn[8][128];
  __shared__ float sA[128], sB[128];
  int t = threadIdx.x;
  for (int i = t; i < 128 * 64; i += 256) sW[i] = W2[i];
  if (t < 128){ sA[t] = a1[t]; sB[t] = b1[t]; }
  __syncthreads();
  int r0 = blockIdx.x * 8;
  for (int i = t; i < 8 * 128; i += 256){
    int ir = i >> 7, k = i & 127;
    int row = r0 + ir;
    float v = 0.f;
    if (row < N) v = (sA[k] * h1[(size_t)row * 128 + k] + sB[k]) * out_n[row];
    sIn[ir][k] = v;
  }
  __syncthreads();
  int c = t & 63;
  int ib = t >> 6;            // 0..3
  float acc[2] = {0.f, 0.f};
  for (int k = 0; k < 128; ++k){
    float w = sW[k * 64 + c];
    acc[0] += sIn[ib + 0][k] * w;
    acc[1] += sIn[ib + 4][k] * w;
  }
  for (int j = 0; j < 2; ++j){
    int row = r0 + ib + 4 * j;
    if (row < N) z[(size_t)row * 64 + c] = acc[j];
  }
}

// ---- stage2 epilogue: h2 = leaky(agg2*in_n) consumed on the fly:
//      global per-feature stats + per-graph segment sums (graph_id sorted) ----
__global__ void post2_kernel(const float* __restrict__ agg, const float* __restrict__ in_n,
                             const int* __restrict__ gid, int N, int chunk,
                             float* __restrict__ sum2, float* __restrict__ sumsq2,
                             float* __restrict__ segsum, float* __restrict__ cnt){
  int f = threadIdx.x;           // 64
  int r0 = blockIdx.x * chunk;
  int r1 = min(N, r0 + chunk);
  if (r0 >= r1) return;
  float s = 0.f, s2 = 0.f;
  int cur = gid[r0];
  float seg = 0.f;
  int run = 0;
  for (int r = r0; r < r1; ++r){
    int g = gid[r];
    if (g != cur){
      atomicAdd(&segsum[(size_t)cur * 64 + f], seg);
      if (f == 0) atomicAdd(&cnt[cur], (float)run);
      seg = 0.f; run = 0; cur = g;
    }
    float v = leaky(agg[(size_t)r * 64 + f] * in_n[r]);
    s += v; s2 += v * v;
    seg += v; ++run;
  }
  atomicAdd(&segsum[(size_t)cur * 64 + f], seg);
  if (f == 0) atomicAdd(&cnt[cur], (float)run);
  atomicAdd(&sum2[f], s);
  atomicAdd(&sumsq2[f], s2);
}

// ---- head: g = a2*segmean+b2 -> (L1,leaky,IN) -> (L2,leaky,IN) -> (L3,leaky,IN) -> Wc ----
// one wave per graph; shuffle reductions within 32/16/8-lane groups.
__global__ void head_kernel(const float* __restrict__ segsum, const float* __restrict__ cnt,
                            const float* __restrict__ a2, const float* __restrict__ b2,
                            const float* __restrict__ L1, const float* __restrict__ L2,
                            const float* __restrict__ L3, const float* __restrict__ Wc,
                            float* __restrict__ out){
  __shared__ float bufA[64];
  __shared__ float bufB[32];
  __shared__ float bufC[8];
  int b = blockIdx.x;
  int j = threadIdx.x;          // 64
  float c = cnt[b];
  float g0 = (c > 0.f) ? (a2[j] * (segsum[(size_t)b * 64 + j] / c) + b2[j]) : 0.f;
  bufA[j] = g0;
  __syncthreads();
  // L1: 64 -> 32, leaky, instnorm over 32 lanes
  float y = 0.f;
  if (j < 32){
    float acc = 0.f;
    for (int f = 0; f < 64; ++f) acc += bufA[f] * L1[f * 32 + j];
    y = leaky(acc);
  }
  float m = y;
  for (int mask = 1; mask <= 16; mask <<= 1) m += __shfl_xor(m, mask);
  m *= (1.f / 32.f);
  float d = y - m;
  float v = d * d;
  for (int mask = 1; mask <= 16; mask <<= 1) v += __shfl_xor(v, mask);
  v *= (1.f / 32.f);
  float yn = d * rsqrtf(v + EPS);
  if (j < 32) bufB[j] = yn;
  __syncthreads();
  // L2: 32 -> 16, leaky, instnorm over 16 lanes
  y = 0.f;
  if (j < 16){
    float acc = 0.f;
    for (int f = 0; f < 32; ++f) acc += bufB[f] * L2[f * 16 + j];
    y = leaky(acc);
  }
  m = y;
  for (int mask = 1; mask <= 8; mask <<= 1) m += __shfl_xor(m, mask);
  m *= (1.f / 16.f);
  d = y - m; v = d * d;
  for (int mask = 1; mask <= 8; mask <<= 1) v += __shfl_xor(v, mask);
  v *= (1.f / 16.f);
  yn = d * rsqrtf(v + EPS);
  if (j < 16) bufA[j] = yn;     // reuse bufA
  __syncthreads();
  // L3: 16 -> 8, leaky, instnorm over 8 lanes
  y = 0.f;
  if (j < 8){
    float acc = 0.f;
    for (int f = 0; f < 16; ++f) acc += bufA[f] * L3[f * 8 + j];
    y = leaky(acc);
  }
  m = y;
  for (int mask = 1; mask <= 4; mask <<= 1) m += __shfl_xor(m, mask);
  m *= (1.f / 8.f);
  d = y - m; v = d * d;
  for (int mask = 1; mask <= 4; mask <<= 1) v += __shfl_xor(v, mask);
  v *= (1.f / 8.f);
  yn = d * rsqrtf(v + EPS);
  if (j < 8) bufC[j] = yn;
  __syncthreads();
  // classifier: 8 -> 16
  if (j < 16){
    float acc = 0.f;
    for (int f = 0; f < 8; ++f) acc += bufC[f] * Wc[f * 16 + j];
    out[(size_t)b * 16 + j] = acc;
  }
}

extern "C" void kernel_launch(void* const* d_in, const int* in_sizes, int n_in,
                              void* d_out, int out_size, void* d_ws, size_t ws_size,
                              hipStream_t stream){
  const float* x   = (const float*)d_in[0];
  const int*   src = (const int*)  d_in[1];
  const int*   dst = (const int*)  d_in[2];
  const float* ew  = (const float*)d_in[3];
  const int*   gid = (const int*)  d_in[4];
  const float* W1  = (const float*)d_in[5];
  const float* g1  = (const float*)d_in[6];
  const float* be1 = (const float*)d_in[7];
  const float* al1 = (const float*)d_in[8];
  const float* W2  = (const float*)d_in[9];
  const float* g2  = (const float*)d_in[10];
  const float* be2 = (const float*)d_in[11];
  const float* al2 = (const float*)d_in[12];
  const float* L1  = (const float*)d_in[13];
  const float* L2  = (const float*)d_in[14];
  const float* L3  = (const float*)d_in[15];
  const float* Wc  = (const float*)d_in[16];
  int N = in_sizes[0] / 64;
  int E = in_sizes[1];
  const int B = 50;

  // workspace layout (floats): ~258*N + 4k  (~51.6 MB at N=50000)
  float* ws = (float*)d_ws;
  size_t off = 0;
  float* norm_out = ws + off; off += N;                 // deg_out -> rsqrt norm
  float* norm_in  = ws + off; off += N;                 // deg_in  -> rsqrt norm
  float* agg      = ws + off; off += (size_t)N * 64;    // conv1 agg, reused for conv2
  float* h1       = ws + off; off += (size_t)N * 128;   // leaky(conv1)
  float* z        = ws + off; off += (size_t)N * 64;    // (h1n*out_n)@W2 pre-scatter
  float* sum1     = ws + off; off += 128;
  float* sumsq1   = ws + off; off += 128;
  float* a1       = ws + off; off += 128;
  float* b1       = ws + off; off += 128;
  float* sum2     = ws + off; off += 64;
  float* sumsq2   = ws + off; off += 64;
  float* a2       = ws + off; off += 64;
  float* b2       = ws + off; off += 64;
  float* segsum   = ws + off; off += (size_t)B * 64;
  float* cnt      = ws + off; off += B;

  // zero accumulators (ws is poisoned 0xAA before every timed launch)
  hipMemsetAsync(norm_out, 0, sizeof(float) * (size_t)2 * N, stream);
  hipMemsetAsync(agg,      0, sizeof(float) * (size_t)N * 64, stream);
  hipMemsetAsync(sum1,     0, sizeof(float) * (4 * 128 + 4 * 64 + (size_t)B * 64 + B), stream);

  deg_kernel <<<(E + 255) / 256, 256, 0, stream>>>(src, dst, norm_out, norm_in, E);
  norm_kernel<<<(N + 255) / 256, 256, 0, stream>>>(norm_out, norm_in, N);

  // conv1: scatter at F=64, then GEMM to 128 (+leaky)
  edge_agg<true><<<(E + 3) / 4, 256, 0, stream>>>(x, src, dst, ew, norm_out, agg, E);
  gemm1_kernel<<<(N + 7) / 8, 256, 0, stream>>>(agg, norm_in, W1, h1, N);
  colstats_kernel<128><<<256, 128, 0, stream>>>(h1, N, sum1, sumsq1);
  finalize_norm<<<1, 128, 0, stream>>>(sum1, sumsq1, g1, be1, al1, a1, b1, 128, 1.f / (float)N);

  // conv2: GEMM to 64 first (norm1 + out_n folded in), then scatter at F=64
  gemm2_kernel<<<(N + 7) / 8, 256, 0, stream>>>(h1, norm_out, a1, b1, W2, z, N);
  hipMemsetAsync(agg, 0, sizeof(float) * (size_t)N * 64, stream);
  edge_agg<false><<<(E + 3) / 4, 256, 0, stream>>>(z, src, dst, ew, nullptr, agg, E);

  // stage2 epilogue: stats + segment sums without materializing h2
  int chunk = (N + 511) / 512;
  post2_kernel<<<512, 64, 0, stream>>>(agg, norm_in, gid, N, chunk, sum2, sumsq2, segsum, cnt);
  finalize_norm<<<1, 64, 0, stream>>>(sum2, sumsq2, g2, be2, al2, a2, b2, 64, 1.f / (float)N);

  head_kernel<<<B, 64, 0, stream>>>(segsum, cnt, a2, b2, L1, L2, L3, Wc, (float*)d_out);
}

// Round 8
// 655.817 us; speedup vs baseline: 1.1363x; 1.1363x over previous
//
#include <hip/hip_runtime.h>
#include <hip/hip_bf16.h>

// GNN pipeline: 2x GraphConv(norm=both, edge_weight) + LeakyReLU + GraphNorm,
// segment-mean readout, 3x (Linear+LeakyReLU+InstanceNorm), classifier.
// R3 -> R4: replaced atomic scatter edge_agg (204.8 MB memory-side atomic
// write-through per conv, 24% HBM peak) with CSR-by-dst + one-wave-per-node
// register accumulation (plain 12.8 MB store). CSR built once, used twice.
#define NEG_SLOPE 0.01f
#define EPS 1e-5f

__device__ __forceinline__ float leaky(float x){ return x > 0.f ? x : NEG_SLOPE * x; }

// ---- degree histograms (int) ----
__global__ void deg_kernel(const int* __restrict__ src, const int* __restrict__ dst,
                           int* __restrict__ iout, int* __restrict__ iin, int E){
  int e = blockIdx.x * blockDim.x + threadIdx.x;
  if (e < E){
    atomicAdd(&iout[src[e]], 1);
    atomicAdd(&iin[dst[e]], 1);
  }
}

// ---- norms: rsqrt(max(deg,1)) ----
__global__ void norm_kernel(const int* __restrict__ iout, const int* __restrict__ iin,
                            float* __restrict__ out_n, float* __restrict__ in_n, int N){
  int i = blockIdx.x * blockDim.x + threadIdx.x;
  if (i < N){
    int a = iout[i], b = iin[i];
    out_n[i] = rsqrtf((float)(a > 0 ? a : 1));
    in_n[i]  = rsqrtf((float)(b > 0 ? b : 1));
  }
}

// ---- exclusive scan of in-degrees -> row_ptr, cursor (single block) ----
__global__ __launch_bounds__(1024) void scan_kernel(const int* __restrict__ iin,
    int* __restrict__ row_ptr, int* __restrict__ cursor, int N){
  __shared__ int part[1024];
  int t = threadIdx.x;
  int chunk = (N + 1023) / 1024;
  int s0 = t * chunk, s1 = min(N, s0 + chunk);
  int loc = 0;
  for (int i = s0; i < s1; ++i) loc += iin[i];
  part[t] = loc;
  __syncthreads();
  for (int off = 1; off < 1024; off <<= 1){
    int v = (t >= off) ? part[t - off] : 0;
    __syncthreads();
    part[t] += v;
    __syncthreads();
  }
  int pre = (t == 0) ? 0 : part[t - 1];
  for (int i = s0; i < s1; ++i){
    row_ptr[i] = pre;
    cursor[i] = pre;
    pre += iin[i];
  }
  if (t == 1023) row_ptr[N] = part[1023];
}

// ---- CSR fill: edges bucketed by dst ----
__global__ void fill_kernel(const int* __restrict__ src, const int* __restrict__ dst,
                            const float* __restrict__ ew, int* __restrict__ cursor,
                            int* __restrict__ esrc, float* __restrict__ eww, int E){
  int e = blockIdx.x * blockDim.x + threadIdx.x;
  if (e < E){
    int d = dst[e];
    int pos = atomicAdd(&cursor[d], 1);
    esrc[pos] = src[e];
    eww[pos] = ew[e];
  }
}

// ---- atomic-free aggregation: one wave per node, lane = feature ----
// MODE 1 (conv1): w = ew*out_n[s]; out = acc*in_n
// MODE 2 (conv2): w = ew (out_n folded in z); out = leaky(acc*in_n)
template<int MODE>
__global__ __launch_bounds__(256) void agg_csr(const float* __restrict__ xin,
    const int* __restrict__ row_ptr, const int* __restrict__ esrc,
    const float* __restrict__ eww, const float* __restrict__ out_n,
    const float* __restrict__ in_n, float* __restrict__ outp, int N){
  int node = (int)((blockIdx.x * (unsigned)blockDim.x + threadIdx.x) >> 6);
  int f = threadIdx.x & 63;
  if (node >= N) return;
  int e0 = row_ptr[node], e1 = row_ptr[node + 1];
  float acc = 0.f;
  #pragma unroll 2
  for (int e = e0; e < e1; ++e){
    int s = esrc[e];
    float w = eww[e];
    if (MODE == 1) w *= out_n[s];
    acc += xin[(size_t)s * 64 + f] * w;
  }
  acc *= in_n[node];
  if (MODE == 2) acc = leaky(acc);
  outp[(size_t)node * 64 + f] = acc;
}

// ---- h1 = leaky(agg1 @ W1)  [Nx64]@[64x128]  (in_n prefolded into agg1) ----
__global__ __launch_bounds__(256) void gemm1_kernel(const float* __restrict__ agg,
    const float* __restrict__ W1, float* __restrict__ h1, int N){
  __shared__ float sW[64 * 128];
  __shared__ float sIn[8][64];
  int t = threadIdx.x;
  for (int i = t; i < 64 * 128; i += 256) sW[i] = W1[i];
  int r0 = blockIdx.x * 8;
  for (int i = t; i < 8 * 64; i += 256){
    int ir = i >> 6, k = i & 63;
    int row = r0 + ir;
    sIn[ir][k] = (row < N) ? agg[(size_t)row * 64 + k] : 0.f;
  }
  __syncthreads();
  int c = t & 127;
  int ib = t >> 7;            // 0..1
  float acc[4] = {0.f, 0.f, 0.f, 0.f};
  for (int k = 0; k < 64; ++k){
    float w = sW[k * 128 + c];
    acc[0] += sIn[ib + 0][k] * w;
    acc[1] += sIn[ib + 2][k] * w;
    acc[2] += sIn[ib + 4][k] * w;
    acc[3] += sIn[ib + 6][k] * w;
  }
  for (int j = 0; j < 4; ++j){
    int row = r0 + ib + 2 * j;
    if (row < N) h1[(size_t)row * 128 + c] = leaky(acc[j]);
  }
}

// ---- per-feature column sums / sums-of-squares ----
template<int F>
__global__ void colstats_kernel(const float* __restrict__ h, int N,
                                float* __restrict__ sum, float* __restrict__ sumsq){
  int f = threadIdx.x;            // blockDim.x == F
  float s = 0.f, s2 = 0.f;
  for (int r = blockIdx.x; r < N; r += gridDim.x){
    float v = h[(size_t)r * F + f];
    s += v; s2 += v * v;
  }
  atomicAdd(&sum[f], s);
  atomicAdd(&sumsq[f], s2);
}

// ---- GraphNorm -> affine: a = g*rsqrt(var+eps), b = beta - a*alpha*mean ----
__global__ void finalize_norm(const float* __restrict__ sum, const float* __restrict__ sumsq,
                              const float* __restrict__ gamma, const float* __restrict__ beta,
                              const float* __restrict__ alpha,
                              float* __restrict__ a, float* __restrict__ b, int F, float invN){
  int f = threadIdx.x;
  if (f < F){
    float m = sum[f] * invN;
    float ex2 = sumsq[f] * invN;
    float al = alpha[f];
    float var = ex2 - m * m * al * (2.f - al);
    float av = gamma[f] * rsqrtf(var + EPS);
    a[f] = av;
    b[f] = beta[f] - av * al * m;
  }
}

// ---- z = ((a1*h1 + b1) * out_n) @ W2   [Nx128]@[128x64] ----
__global__ __launch_bounds__(256) void gemm2_kernel(const float* __restrict__ h1,
    const float* __restrict__ out_n, const float* __restrict__ a1, const float* __restrict__ b1,
    const float* __restrict__ W2, float* __restrict__ z, int N){
  __shared__ float sW[128 * 64];
  __shared__ float sIn[8][128];
  __shared__ float sA[128], sB[128];
  int t = threadIdx.x;
  for (int i = t; i < 128 * 64; i += 256) sW[i] = W2[i];
  if (t < 128){ sA[t] = a1[t]; sB[t] = b1[t]; }
  __syncthreads();
  int r0 = blockIdx.x * 8;
  for (int i = t; i < 8 * 128; i += 256){
    int ir = i >> 7, k = i & 127;
    int row = r0 + ir;
    float v = 0.f;
    if (row < N) v = (sA[k] * h1[(size_t)row * 128 + k] + sB[k]) * out_n[row];
    sIn[ir][k] = v;
  }
  __syncthreads();
  int c = t & 63;
  int ib = t >> 6;            // 0..3
  float acc[2] = {0.f, 0.f};
  for (int k = 0; k < 128; ++k){
    float w = sW[k * 64 + c];
    acc[0] += sIn[ib + 0][k] * w;
    acc[1] += sIn[ib + 4][k] * w;
  }
  for (int j = 0; j < 2; ++j){
    int row = r0 + ib + 4 * j;
    if (row < N) z[(size_t)row * 64 + c] = acc[j];
  }
}

// ---- stage2 epilogue: hv = leaky(agg2*in_n) already materialized by agg_csr<2>;
//      global per-feature stats + per-graph segment sums (graph_id sorted) ----
__global__ void post2_kernel(const float* __restrict__ hv, const int* __restrict__ gid,
                             int N, int chunk,
                             float* __restrict__ sum2, float* __restrict__ sumsq2,
                             float* __restrict__ segsum, float* __restrict__ cnt){
  int f = threadIdx.x;           // 64
  int r0 = blockIdx.x * chunk;
  int r1 = min(N, r0 + chunk);
  if (r0 >= r1) return;
  float s = 0.f, s2 = 0.f;
  int cur = gid[r0];
  float seg = 0.f;
  int run = 0;
  for (int r = r0; r < r1; ++r){
    int g = gid[r];
    if (g != cur){
      atomicAdd(&segsum[(size_t)cur * 64 + f], seg);
      if (f == 0) atomicAdd(&cnt[cur], (float)run);
      seg = 0.f; run = 0; cur = g;
    }
    float v = hv[(size_t)r * 64 + f];
    s += v; s2 += v * v;
    seg += v; ++run;
  }
  atomicAdd(&segsum[(size_t)cur * 64 + f], seg);
  if (f == 0) atomicAdd(&cnt[cur], (float)run);
  atomicAdd(&sum2[f], s);
  atomicAdd(&sumsq2[f], s2);
}

// ---- head: g = a2*segmean+b2 -> (L1,leaky,IN) -> (L2,leaky,IN) -> (L3,leaky,IN) -> Wc ----
__global__ void head_kernel(const float* __restrict__ segsum, const float* __restrict__ cnt,
                            const float* __restrict__ a2, const float* __restrict__ b2,
                            const float* __restrict__ L1, const float* __restrict__ L2,
                            const float* __restrict__ L3, const float* __restrict__ Wc,
                            float* __restrict__ out){
  __shared__ float bufA[64];
  __shared__ float bufB[32];
  __shared__ float bufC[8];
  int b = blockIdx.x;
  int j = threadIdx.x;          // 64
  float c = cnt[b];
  float g0 = (c > 0.f) ? (a2[j] * (segsum[(size_t)b * 64 + j] / c) + b2[j]) : 0.f;
  bufA[j] = g0;
  __syncthreads();
  // L1: 64 -> 32, leaky, instnorm over 32 lanes
  float y = 0.f;
  if (j < 32){
    float acc = 0.f;
    for (int f = 0; f < 64; ++f) acc += bufA[f] * L1[f * 32 + j];
    y = leaky(acc);
  }
  float m = y;
  for (int mask = 1; mask <= 16; mask <<= 1) m += __shfl_xor(m, mask);
  m *= (1.f / 32.f);
  float d = y - m;
  float v = d * d;
  for (int mask = 1; mask <= 16; mask <<= 1) v += __shfl_xor(v, mask);
  v *= (1.f / 32.f);
  float yn = d * rsqrtf(v + EPS);
  if (j < 32) bufB[j] = yn;
  __syncthreads();
  // L2: 32 -> 16, leaky, instnorm over 16 lanes
  y = 0.f;
  if (j < 16){
    float acc = 0.f;
    for (int f = 0; f < 32; ++f) acc += bufB[f] * L2[f * 16 + j];
    y = leaky(acc);
  }
  m = y;
  for (int mask = 1; mask <= 8; mask <<= 1) m += __shfl_xor(m, mask);
  m *= (1.f / 16.f);
  d = y - m; v = d * d;
  for (int mask = 1; mask <= 8; mask <<= 1) v += __shfl_xor(v, mask);
  v *= (1.f / 16.f);
  yn = d * rsqrtf(v + EPS);
  if (j < 16) bufA[j] = yn;     // reuse bufA
  __syncthreads();
  // L3: 16 -> 8, leaky, instnorm over 8 lanes
  y = 0.f;
  if (j < 8){
    float acc = 0.f;
    for (int f = 0; f < 16; ++f) acc += bufA[f] * L3[f * 8 + j];
    y = leaky(acc);
  }
  m = y;
  for (int mask = 1; mask <= 4; mask <<= 1) m += __shfl_xor(m, mask);
  m *= (1.f / 8.f);
  d = y - m; v = d * d;
  for (int mask = 1; mask <= 4; mask <<= 1) v += __shfl_xor(v, mask);
  v *= (1.f / 8.f);
  yn = d * rsqrtf(v + EPS);
  if (j < 8) bufC[j] = yn;
  __syncthreads();
  // classifier: 8 -> 16
  if (j < 16){
    float acc = 0.f;
    for (int f = 0; f < 8; ++f) acc += bufC[f] * Wc[f * 16 + j];
    out[(size_t)b * 16 + j] = acc;
  }
}

extern "C" void kernel_launch(void* const* d_in, const int* in_sizes, int n_in,
                              void* d_out, int out_size, void* d_ws, size_t ws_size,
                              hipStream_t stream){
  const float* x   = (const float*)d_in[0];
  const int*   src = (const int*)  d_in[1];
  const int*   dst = (const int*)  d_in[2];
  const float* ew  = (const float*)d_in[3];
  const int*   gid = (const int*)  d_in[4];
  const float* W1  = (const float*)d_in[5];
  const float* g1  = (const float*)d_in[6];
  const float* be1 = (const float*)d_in[7];
  const float* al1 = (const float*)d_in[8];
  const float* W2  = (const float*)d_in[9];
  const float* g2  = (const float*)d_in[10];
  const float* be2 = (const float*)d_in[11];
  const float* al2 = (const float*)d_in[12];
  const float* L1  = (const float*)d_in[13];
  const float* L2  = (const float*)d_in[14];
  const float* L3  = (const float*)d_in[15];
  const float* Wc  = (const float*)d_in[16];
  int N = in_sizes[0] / 64;
  int E = in_sizes[1];
  const int B = 50;

  // workspace layout: ints then floats (~46 MB total; buffers reused across stages)
  char* wsb = (char*)d_ws;
  size_t off = 0;
  int* iout    = (int*)(wsb + off); off += sizeof(int) * (size_t)N;      // -> cursor reuse
  int* iin     = (int*)(wsb + off); off += sizeof(int) * (size_t)N;
  int* row_ptr = (int*)(wsb + off); off += sizeof(int) * ((size_t)N + 1);
  int* esrc    = (int*)(wsb + off); off += sizeof(int) * (size_t)E;
  float* eww   = (float*)(wsb + off); off += sizeof(float) * (size_t)E;
  float* out_n = (float*)(wsb + off); off += sizeof(float) * (size_t)N;
  float* in_n  = (float*)(wsb + off); off += sizeof(float) * (size_t)N;
  float* P     = (float*)(wsb + off); off += sizeof(float) * (size_t)N * 64;   // agg1, then z
  float* H     = (float*)(wsb + off); off += sizeof(float) * (size_t)N * 128;  // h1, then hv
  float* sum1  = (float*)(wsb + off); off += sizeof(float) * 128;
  float* sumsq1= (float*)(wsb + off); off += sizeof(float) * 128;
  float* a1    = (float*)(wsb + off); off += sizeof(float) * 128;
  float* b1    = (float*)(wsb + off); off += sizeof(float) * 128;
  float* sum2  = (float*)(wsb + off); off += sizeof(float) * 64;
  float* sumsq2= (float*)(wsb + off); off += sizeof(float) * 64;
  float* a2    = (float*)(wsb + off); off += sizeof(float) * 64;
  float* b2    = (float*)(wsb + off); off += sizeof(float) * 64;
  float* segsum= (float*)(wsb + off); off += sizeof(float) * (size_t)B * 64;
  float* cnt   = (float*)(wsb + off); off += sizeof(float) * B;
  int* cursor  = iout;  // iout dead after norm_kernel; scan initializes cursor

  // zero: degree histograms + stats block (ws is poisoned 0xAA每 launch)
  hipMemsetAsync(iout, 0, sizeof(int) * (size_t)2 * N, stream);
  hipMemsetAsync(sum1, 0, sizeof(float) * (4 * 128 + 4 * 64 + (size_t)B * 64 + B), stream);

  // degrees + norms + CSR (built once, used by both convs)
  deg_kernel <<<(E + 255) / 256, 256, 0, stream>>>(src, dst, iout, iin, E);
  norm_kernel<<<(N + 255) / 256, 256, 0, stream>>>(iout, iin, out_n, in_n, N);
  scan_kernel<<<1, 1024, 0, stream>>>(iin, row_ptr, cursor, N);
  fill_kernel<<<(E + 255) / 256, 256, 0, stream>>>(src, dst, ew, cursor, esrc, eww, E);

  // conv1: atomic-free gather-reduce at F=64, then GEMM to 128 (+leaky)
  agg_csr<1><<<(N * 64 + 255) / 256, 256, 0, stream>>>(x, row_ptr, esrc, eww, out_n, in_n, P, N);
  gemm1_kernel<<<(N + 7) / 8, 256, 0, stream>>>(P, W1, H, N);
  colstats_kernel<128><<<256, 128, 0, stream>>>(H, N, sum1, sumsq1);
  finalize_norm<<<1, 128, 0, stream>>>(sum1, sumsq1, g1, be1, al1, a1, b1, 128, 1.f / (float)N);

  // conv2: GEMM to 64 first (norm1 + out_n folded), then gather-reduce (leaky+in_n folded)
  gemm2_kernel<<<(N + 7) / 8, 256, 0, stream>>>(H, out_n, a1, b1, W2, P, N);
  agg_csr<2><<<(N * 64 + 255) / 256, 256, 0, stream>>>(P, row_ptr, esrc, eww, nullptr, in_n, H, N);

  // stage2 epilogue: stats + segment sums over hv (=H)
  int chunk = (N + 1023) / 1024;
  post2_kernel<<<1024, 64, 0, stream>>>(H, gid, N, chunk, sum2, sumsq2, segsum, cnt);
  finalize_norm<<<1, 64, 0, stream>>>(sum2, sumsq2, g2, be2, al2, a2, b2, 64, 1.f / (float)N);

  head_kernel<<<B, 64, 0, stream>>>(segsum, cnt, a2, b2, L1, L2, L3, Wc, (float*)d_out);
}

// Round 12
// 566.304 us; speedup vs baseline: 1.3159x; 1.1581x over previous
//
#include <hip/hip_runtime.h>
#include <hip/hip_bf16.h>

// GNN pipeline: 2x GraphConv(norm=both, edge_weight) + LeakyReLU + GraphNorm,
// segment-mean readout, 3x (Linear+LeakyReLU+InstanceNorm), classifier.
// R3 -> R4: atomic scatter -> CSR-by-dst + register-accum gather (745->656us).
// R8 -> R9: single-block scan (110us, 0.14% occupancy, #1 dispatch) ->
//           3-kernel parallel scan (blocksum -> offsets -> write), ~15us.
#define NEG_SLOPE 0.01f
#define EPS 1e-5f

__device__ __forceinline__ float leaky(float x){ return x > 0.f ? x : NEG_SLOPE * x; }

// ---- degree histograms (int) ----
__global__ void deg_kernel(const int* __restrict__ src, const int* __restrict__ dst,
                           int* __restrict__ iout, int* __restrict__ iin, int E){
  int e = blockIdx.x * blockDim.x + threadIdx.x;
  if (e < E){
    atomicAdd(&iout[src[e]], 1);
    atomicAdd(&iin[dst[e]], 1);
  }
}

// ---- norms: rsqrt(max(deg,1)) ----
__global__ void norm_kernel(const int* __restrict__ iout, const int* __restrict__ iin,
                            float* __restrict__ out_n, float* __restrict__ in_n, int N){
  int i = blockIdx.x * blockDim.x + threadIdx.x;
  if (i < N){
    int a = iout[i], b = iin[i];
    out_n[i] = rsqrtf((float)(a > 0 ? a : 1));
    in_n[i]  = rsqrtf((float)(b > 0 ? b : 1));
  }
}

// ---- parallel exclusive scan, phase A: per-block (256-wide) sums ----
__global__ __launch_bounds__(256) void scan_blocksum(const int* __restrict__ iin,
                                                     int* __restrict__ bsum, int N){
  __shared__ int sm[256];
  int t = threadIdx.x;
  int i = blockIdx.x * 256 + t;
  sm[t] = (i < N) ? iin[i] : 0;
  __syncthreads();
  for (int off = 128; off > 0; off >>= 1){
    if (t < off) sm[t] += sm[t + off];
    __syncthreads();
  }
  if (t == 0) bsum[blockIdx.x] = sm[0];
}

// ---- phase B: single block scans the block sums (nb <= 1024) ----
__global__ __launch_bounds__(1024) void scan_offsets(const int* __restrict__ bsum,
    int* __restrict__ boff, int nb, int* __restrict__ row_ptr, int N){
  __shared__ int sm[1024];
  int t = threadIdx.x;
  sm[t] = (t < nb) ? bsum[t] : 0;
  __syncthreads();
  for (int off = 1; off < 1024; off <<= 1){
    int v = (t >= off) ? sm[t - off] : 0;
    __syncthreads();
    sm[t] += v;
    __syncthreads();
  }
  if (t < nb) boff[t] = (t == 0) ? 0 : sm[t - 1];
  if (t == 1023) row_ptr[N] = sm[1023];   // total edge count
}

// ---- phase C: block-local exclusive scan + block offset -> row_ptr, cursor ----
__global__ __launch_bounds__(256) void scan_write(const int* __restrict__ iin,
    const int* __restrict__ boff, int* __restrict__ row_ptr, int* __restrict__ cursor, int N){
  __shared__ int sm[256];
  int t = threadIdx.x;
  int i = blockIdx.x * 256 + t;
  int v = (i < N) ? iin[i] : 0;
  sm[t] = v;
  __syncthreads();
  for (int off = 1; off < 256; off <<= 1){
    int u = (t >= off) ? sm[t - off] : 0;
    __syncthreads();
    sm[t] += u;
    __syncthreads();
  }
  int excl = sm[t] - v + boff[blockIdx.x];
  if (i < N){ row_ptr[i] = excl; cursor[i] = excl; }
}

// ---- CSR fill: edges bucketed by dst ----
__global__ void fill_kernel(const int* __restrict__ src, const int* __restrict__ dst,
                            const float* __restrict__ ew, int* __restrict__ cursor,
                            int* __restrict__ esrc, float* __restrict__ eww, int E){
  int e = blockIdx.x * blockDim.x + threadIdx.x;
  if (e < E){
    int d = dst[e];
    int pos = atomicAdd(&cursor[d], 1);
    esrc[pos] = src[e];
    eww[pos] = ew[e];
  }
}

// ---- atomic-free aggregation: one wave per node, lane = feature ----
// MODE 1 (conv1): w = ew*out_n[s]; out = acc*in_n
// MODE 2 (conv2): w = ew (out_n folded in z); out = leaky(acc*in_n)
template<int MODE>
__global__ __launch_bounds__(256) void agg_csr(const float* __restrict__ xin,
    const int* __restrict__ row_ptr, const int* __restrict__ esrc,
    const float* __restrict__ eww, const float* __restrict__ out_n,
    const float* __restrict__ in_n, float* __restrict__ outp, int N){
  int node = (int)((blockIdx.x * (unsigned)blockDim.x + threadIdx.x) >> 6);
  int f = threadIdx.x & 63;
  if (node >= N) return;
  int e0 = row_ptr[node], e1 = row_ptr[node + 1];
  float acc = 0.f;
  #pragma unroll 2
  for (int e = e0; e < e1; ++e){
    int s = esrc[e];
    float w = eww[e];
    if (MODE == 1) w *= out_n[s];
    acc += xin[(size_t)s * 64 + f] * w;
  }
  acc *= in_n[node];
  if (MODE == 2) acc = leaky(acc);
  outp[(size_t)node * 64 + f] = acc;
}

// ---- h1 = leaky(agg1 @ W1)  [Nx64]@[64x128]  (in_n prefolded into agg1) ----
__global__ __launch_bounds__(256) void gemm1_kernel(const float* __restrict__ agg,
    const float* __restrict__ W1, float* __restrict__ h1, int N){
  __shared__ float sW[64 * 128];
  __shared__ float sIn[8][64];
  int t = threadIdx.x;
  for (int i = t; i < 64 * 128; i += 256) sW[i] = W1[i];
  int r0 = blockIdx.x * 8;
  for (int i = t; i < 8 * 64; i += 256){
    int ir = i >> 6, k = i & 63;
    int row = r0 + ir;
    sIn[ir][k] = (row < N) ? agg[(size_t)row * 64 + k] : 0.f;
  }
  __syncthreads();
  int c = t & 127;
  int ib = t >> 7;            // 0..1
  float acc[4] = {0.f, 0.f, 0.f, 0.f};
  for (int k = 0; k < 64; ++k){
    float w = sW[k * 128 + c];
    acc[0] += sIn[ib + 0][k] * w;
    acc[1] += sIn[ib + 2][k] * w;
    acc[2] += sIn[ib + 4][k] * w;
    acc[3] += sIn[ib + 6][k] * w;
  }
  for (int j = 0; j < 4; ++j){
    int row = r0 + ib + 2 * j;
    if (row < N) h1[(size_t)row * 128 + c] = leaky(acc[j]);
  }
}

// ---- per-feature column sums / sums-of-squares ----
template<int F>
__global__ void colstats_kernel(const float* __restrict__ h, int N,
                                float* __restrict__ sum, float* __restrict__ sumsq){
  int f = threadIdx.x;            // blockDim.x == F
  float s = 0.f, s2 = 0.f;
  for (int r = blockIdx.x; r < N; r += gridDim.x){
    float v = h[(size_t)r * F + f];
    s += v; s2 += v * v;
  }
  atomicAdd(&sum[f], s);
  atomicAdd(&sumsq[f], s2);
}

// ---- GraphNorm -> affine: a = g*rsqrt(var+eps), b = beta - a*alpha*mean ----
__global__ void finalize_norm(const float* __restrict__ sum, const float* __restrict__ sumsq,
                              const float* __restrict__ gamma, const float* __restrict__ beta,
                              const float* __restrict__ alpha,
                              float* __restrict__ a, float* __restrict__ b, int F, float invN){
  int f = threadIdx.x;
  if (f < F){
    float m = sum[f] * invN;
    float ex2 = sumsq[f] * invN;
    float al = alpha[f];
    float var = ex2 - m * m * al * (2.f - al);
    float av = gamma[f] * rsqrtf(var + EPS);
    a[f] = av;
    b[f] = beta[f] - av * al * m;
  }
}

// ---- z = ((a1*h1 + b1) * out_n) @ W2   [Nx128]@[128x64] ----
__global__ __launch_bounds__(256) void gemm2_kernel(const float* __restrict__ h1,
    const float* __restrict__ out_n, const float* __restrict__ a1, const float* __restrict__ b1,
    const float* __restrict__ W2, float* __restrict__ z, int N){
  __shared__ float sW[128 * 64];
  __shared__ float sIn[8][128];
  __shared__ float sA[128], sB[128];
  int t = threadIdx.x;
  for (int i = t; i < 128 * 64; i += 256) sW[i] = W2[i];
  if (t < 128){ sA[t] = a1[t]; sB[t] = b1[t]; }
  __syncthreads();
  int r0 = blockIdx.x * 8;
  for (int i = t; i < 8 * 128; i += 256){
    int ir = i >> 7, k = i & 127;
    int row = r0 + ir;
    float v = 0.f;
    if (row < N) v = (sA[k] * h1[(size_t)row * 128 + k] + sB[k]) * out_n[row];
    sIn[ir][k] = v;
  }
  __syncthreads();
  int c = t & 63;
  int ib = t >> 6;            // 0..3
  float acc[2] = {0.f, 0.f};
  for (int k = 0; k < 128; ++k){
    float w = sW[k * 64 + c];
    acc[0] += sIn[ib + 0][k] * w;
    acc[1] += sIn[ib + 4][k] * w;
  }
  for (int j = 0; j < 2; ++j){
    int row = r0 + ib + 4 * j;
    if (row < N) z[(size_t)row * 64 + c] = acc[j];
  }
}

// ---- stage2 epilogue: hv = leaky(agg2*in_n) already materialized by agg_csr<2>;
//      global per-feature stats + per-graph segment sums (graph_id sorted) ----
__global__ void post2_kernel(const float* __restrict__ hv, const int* __restrict__ gid,
                             int N, int chunk,
                             float* __restrict__ sum2, float* __restrict__ sumsq2,
                             float* __restrict__ segsum, float* __restrict__ cnt){
  int f = threadIdx.x;           // 64
  int r0 = blockIdx.x * chunk;
  int r1 = min(N, r0 + chunk);
  if (r0 >= r1) return;
  float s = 0.f, s2 = 0.f;
  int cur = gid[r0];
  float seg = 0.f;
  int run = 0;
  for (int r = r0; r < r1; ++r){
    int g = gid[r];
    if (g != cur){
      atomicAdd(&segsum[(size_t)cur * 64 + f], seg);
      if (f == 0) atomicAdd(&cnt[cur], (float)run);
      seg = 0.f; run = 0; cur = g;
    }
    float v = hv[(size_t)r * 64 + f];
    s += v; s2 += v * v;
    seg += v; ++run;
  }
  atomicAdd(&segsum[(size_t)cur * 64 + f], seg);
  if (f == 0) atomicAdd(&cnt[cur], (float)run);
  atomicAdd(&sum2[f], s);
  atomicAdd(&sumsq2[f], s2);
}

// ---- head: g = a2*segmean+b2 -> (L1,leaky,IN) -> (L2,leaky,IN) -> (L3,leaky,IN) -> Wc ----
__global__ void head_kernel(const float* __restrict__ segsum, const float* __restrict__ cnt,
                            const float* __restrict__ a2, const float* __restrict__ b2,
                            const float* __restrict__ L1, const float* __restrict__ L2,
                            const float* __restrict__ L3, const float* __restrict__ Wc,
                            float* __restrict__ out){
  __shared__ float bufA[64];
  __shared__ float bufB[32];
  __shared__ float bufC[8];
  int b = blockIdx.x;
  int j = threadIdx.x;          // 64
  float c = cnt[b];
  float g0 = (c > 0.f) ? (a2[j] * (segsum[(size_t)b * 64 + j] / c) + b2[j]) : 0.f;
  bufA[j] = g0;
  __syncthreads();
  // L1: 64 -> 32, leaky, instnorm over 32 lanes
  float y = 0.f;
  if (j < 32){
    float acc = 0.f;
    for (int f = 0; f < 64; ++f) acc += bufA[f] * L1[f * 32 + j];
    y = leaky(acc);
  }
  float m = y;
  for (int mask = 1; mask <= 16; mask <<= 1) m += __shfl_xor(m, mask);
  m *= (1.f / 32.f);
  float d = y - m;
  float v = d * d;
  for (int mask = 1; mask <= 16; mask <<= 1) v += __shfl_xor(v, mask);
  v *= (1.f / 32.f);
  float yn = d * rsqrtf(v + EPS);
  if (j < 32) bufB[j] = yn;
  __syncthreads();
  // L2: 32 -> 16, leaky, instnorm over 16 lanes
  y = 0.f;
  if (j < 16){
    float acc = 0.f;
    for (int f = 0; f < 32; ++f) acc += bufB[f] * L2[f * 16 + j];
    y = leaky(acc);
  }
  m = y;
  for (int mask = 1; mask <= 8; mask <<= 1) m += __shfl_xor(m, mask);
  m *= (1.f / 16.f);
  d = y - m; v = d * d;
  for (int mask = 1; mask <= 8; mask <<= 1) v += __shfl_xor(v, mask);
  v *= (1.f / 16.f);
  yn = d * rsqrtf(v + EPS);
  if (j < 16) bufA[j] = yn;     // reuse bufA
  __syncthreads();
  // L3: 16 -> 8, leaky, instnorm over 8 lanes
  y = 0.f;
  if (j < 8){
    float acc = 0.f;
    for (int f = 0; f < 16; ++f) acc += bufA[f] * L3[f * 8 + j];
    y = leaky(acc);
  }
  m = y;
  for (int mask = 1; mask <= 4; mask <<= 1) m += __shfl_xor(m, mask);
  m *= (1.f / 8.f);
  d = y - m; v = d * d;
  for (int mask = 1; mask <= 4; mask <<= 1) v += __shfl_xor(v, mask);
  v *= (1.f / 8.f);
  yn = d * rsqrtf(v + EPS);
  if (j < 8) bufC[j] = yn;
  __syncthreads();
  // classifier: 8 -> 16
  if (j < 16){
    float acc = 0.f;
    for (int f = 0; f < 8; ++f) acc += bufC[f] * Wc[f * 16 + j];
    out[(size_t)b * 16 + j] = acc;
  }
}

extern "C" void kernel_launch(void* const* d_in, const int* in_sizes, int n_in,
                              void* d_out, int out_size, void* d_ws, size_t ws_size,
                              hipStream_t stream){
  const float* x   = (const float*)d_in[0];
  const int*   src = (const int*)  d_in[1];
  const int*   dst = (const int*)  d_in[2];
  const float* ew  = (const float*)d_in[3];
  const int*   gid = (const int*)  d_in[4];
  const float* W1  = (const float*)d_in[5];
  const float* g1  = (const float*)d_in[6];
  const float* be1 = (const float*)d_in[7];
  const float* al1 = (const float*)d_in[8];
  const float* W2  = (const float*)d_in[9];
  const float* g2  = (const float*)d_in[10];
  const float* be2 = (const float*)d_in[11];
  const float* al2 = (const float*)d_in[12];
  const float* L1  = (const float*)d_in[13];
  const float* L2  = (const float*)d_in[14];
  const float* L3  = (const float*)d_in[15];
  const float* Wc  = (const float*)d_in[16];
  int N = in_sizes[0] / 64;
  int E = in_sizes[1];
  const int B = 50;
  int nb = (N + 255) / 256;     // scan blocks (196 at N=50000; supports <= 1024)

  // workspace layout: ints then floats (~46 MB total; buffers reused across stages)
  char* wsb = (char*)d_ws;
  size_t off = 0;
  int* iout    = (int*)(wsb + off); off += sizeof(int) * (size_t)N;      // -> cursor reuse
  int* iin     = (int*)(wsb + off); off += sizeof(int) * (size_t)N;
  int* row_ptr = (int*)(wsb + off); off += sizeof(int) * ((size_t)N + 1);
  int* bsum    = (int*)(wsb + off); off += sizeof(int) * 1024;
  int* boff    = (int*)(wsb + off); off += sizeof(int) * 1024;
  int* esrc    = (int*)(wsb + off); off += sizeof(int) * (size_t)E;
  float* eww   = (float*)(wsb + off); off += sizeof(float) * (size_t)E;
  float* out_n = (float*)(wsb + off); off += sizeof(float) * (size_t)N;
  float* in_n  = (float*)(wsb + off); off += sizeof(float) * (size_t)N;
  float* P     = (float*)(wsb + off); off += sizeof(float) * (size_t)N * 64;   // agg1, then z
  float* H     = (float*)(wsb + off); off += sizeof(float) * (size_t)N * 128;  // h1, then hv
  float* sum1  = (float*)(wsb + off); off += sizeof(float) * 128;
  float* sumsq1= (float*)(wsb + off); off += sizeof(float) * 128;
  float* a1    = (float*)(wsb + off); off += sizeof(float) * 128;
  float* b1    = (float*)(wsb + off); off += sizeof(float) * 128;
  float* sum2  = (float*)(wsb + off); off += sizeof(float) * 64;
  float* sumsq2= (float*)(wsb + off); off += sizeof(float) * 64;
  float* a2    = (float*)(wsb + off); off += sizeof(float) * 64;
  float* b2    = (float*)(wsb + off); off += sizeof(float) * 64;
  float* segsum= (float*)(wsb + off); off += sizeof(float) * (size_t)B * 64;
  float* cnt   = (float*)(wsb + off); off += sizeof(float) * B;
  int* cursor  = iout;  // iout dead after norm_kernel; scan_write initializes cursor

  // zero: degree histograms + stats block (ws is poisoned 0xAA every launch)
  hipMemsetAsync(iout, 0, sizeof(int) * (size_t)2 * N, stream);
  hipMemsetAsync(sum1, 0, sizeof(float) * (4 * 128 + 4 * 64 + (size_t)B * 64 + B), stream);

  // degrees + norms + CSR (built once, used by both convs)
  deg_kernel <<<(E + 255) / 256, 256, 0, stream>>>(src, dst, iout, iin, E);
  norm_kernel<<<(N + 255) / 256, 256, 0, stream>>>(iout, iin, out_n, in_n, N);
  scan_blocksum<<<nb, 256, 0, stream>>>(iin, bsum, N);
  scan_offsets <<<1, 1024, 0, stream>>>(bsum, boff, nb, row_ptr, N);
  scan_write   <<<nb, 256, 0, stream>>>(iin, boff, row_ptr, cursor, N);
  fill_kernel<<<(E + 255) / 256, 256, 0, stream>>>(src, dst, ew, cursor, esrc, eww, E);

  // conv1: atomic-free gather-reduce at F=64, then GEMM to 128 (+leaky)
  agg_csr<1><<<(N * 64 + 255) / 256, 256, 0, stream>>>(x, row_ptr, esrc, eww, out_n, in_n, P, N);
  gemm1_kernel<<<(N + 7) / 8, 256, 0, stream>>>(P, W1, H, N);
  colstats_kernel<128><<<256, 128, 0, stream>>>(H, N, sum1, sumsq1);
  finalize_norm<<<1, 128, 0, stream>>>(sum1, sumsq1, g1, be1, al1, a1, b1, 128, 1.f / (float)N);

  // conv2: GEMM to 64 first (norm1 + out_n folded), then gather-reduce (leaky+in_n folded)
  gemm2_kernel<<<(N + 7) / 8, 256, 0, stream>>>(H, out_n, a1, b1, W2, P, N);
  agg_csr<2><<<(N * 64 + 255) / 256, 256, 0, stream>>>(P, row_ptr, esrc, eww, nullptr, in_n, H, N);

  // stage2 epilogue: stats + segment sums over hv (=H)
  int chunk = (N + 1023) / 1024;
  post2_kernel<<<1024, 64, 0, stream>>>(H, gid, N, chunk, sum2, sumsq2, segsum, cnt);
  finalize_norm<<<1, 64, 0, stream>>>(sum2, sumsq2, g2, be2, al2, a2, b2, 64, 1.f / (float)N);

  head_kernel<<<B, 64, 0, stream>>>(segsum, cnt, a2, b2, L1, L2, L3, Wc, (float*)d_out);
}

// Round 14
// 492.738 us; speedup vs baseline: 1.5124x; 1.1493x over previous
//
#include <hip/hip_runtime.h>
#include <hip/hip_bf16.h>

// GNN pipeline: 2x GraphConv(norm=both, edge_weight) + LeakyReLU + GraphNorm,
// segment-mean readout, 3x (Linear+LeakyReLU+InstanceNorm), classifier.
// R3 -> R4:  atomic scatter -> CSR-by-dst gather (745->656us).
// R8 -> R9:  single-block scan -> 3-kernel parallel scan (656->566us).
// R12 -> R13: gemm1/gemm2 rewrite (81us @ 10% occupancy -> target ~15us):
//   64 rows/block (8x weight-staging amortization), float4 staging,
//   register blocking 16(8) rows x 2 cols, k-tiled-by-4 float4 broadcast reads.
#define NEG_SLOPE 0.01f
#define EPS 1e-5f

__device__ __forceinline__ float leaky(float x){ return x > 0.f ? x : NEG_SLOPE * x; }

// ---- degree histograms (int) ----
__global__ void deg_kernel(const int* __restrict__ src, const int* __restrict__ dst,
                           int* __restrict__ iout, int* __restrict__ iin, int E){
  int e = blockIdx.x * blockDim.x + threadIdx.x;
  if (e < E){
    atomicAdd(&iout[src[e]], 1);
    atomicAdd(&iin[dst[e]], 1);
  }
}

// ---- norms: rsqrt(max(deg,1)) ----
__global__ void norm_kernel(const int* __restrict__ iout, const int* __restrict__ iin,
                            float* __restrict__ out_n, float* __restrict__ in_n, int N){
  int i = blockIdx.x * blockDim.x + threadIdx.x;
  if (i < N){
    int a = iout[i], b = iin[i];
    out_n[i] = rsqrtf((float)(a > 0 ? a : 1));
    in_n[i]  = rsqrtf((float)(b > 0 ? b : 1));
  }
}

// ---- parallel exclusive scan, phase A: per-block (256-wide) sums ----
__global__ __launch_bounds__(256) void scan_blocksum(const int* __restrict__ iin,
                                                     int* __restrict__ bsum, int N){
  __shared__ int sm[256];
  int t = threadIdx.x;
  int i = blockIdx.x * 256 + t;
  sm[t] = (i < N) ? iin[i] : 0;
  __syncthreads();
  for (int off = 128; off > 0; off >>= 1){
    if (t < off) sm[t] += sm[t + off];
    __syncthreads();
  }
  if (t == 0) bsum[blockIdx.x] = sm[0];
}

// ---- phase B: single block scans the block sums (nb <= 1024) ----
__global__ __launch_bounds__(1024) void scan_offsets(const int* __restrict__ bsum,
    int* __restrict__ boff, int nb, int* __restrict__ row_ptr, int N){
  __shared__ int sm[1024];
  int t = threadIdx.x;
  sm[t] = (t < nb) ? bsum[t] : 0;
  __syncthreads();
  for (int off = 1; off < 1024; off <<= 1){
    int v = (t >= off) ? sm[t - off] : 0;
    __syncthreads();
    sm[t] += v;
    __syncthreads();
  }
  if (t < nb) boff[t] = (t == 0) ? 0 : sm[t - 1];
  if (t == 1023) row_ptr[N] = sm[1023];   // total edge count
}

// ---- phase C: block-local exclusive scan + block offset -> row_ptr, cursor ----
__global__ __launch_bounds__(256) void scan_write(const int* __restrict__ iin,
    const int* __restrict__ boff, int* __restrict__ row_ptr, int* __restrict__ cursor, int N){
  __shared__ int sm[256];
  int t = threadIdx.x;
  int i = blockIdx.x * 256 + t;
  int v = (i < N) ? iin[i] : 0;
  sm[t] = v;
  __syncthreads();
  for (int off = 1; off < 256; off <<= 1){
    int u = (t >= off) ? sm[t - off] : 0;
    __syncthreads();
    sm[t] += u;
    __syncthreads();
  }
  int excl = sm[t] - v + boff[blockIdx.x];
  if (i < N){ row_ptr[i] = excl; cursor[i] = excl; }
}

// ---- CSR fill: edges bucketed by dst ----
__global__ void fill_kernel(const int* __restrict__ src, const int* __restrict__ dst,
                            const float* __restrict__ ew, int* __restrict__ cursor,
                            int* __restrict__ esrc, float* __restrict__ eww, int E){
  int e = blockIdx.x * blockDim.x + threadIdx.x;
  if (e < E){
    int d = dst[e];
    int pos = atomicAdd(&cursor[d], 1);
    esrc[pos] = src[e];
    eww[pos] = ew[e];
  }
}

// ---- atomic-free aggregation: one wave per node, lane = feature ----
// MODE 1 (conv1): w = ew*out_n[s]; out = acc*in_n
// MODE 2 (conv2): w = ew (out_n folded in z); out = leaky(acc*in_n)
template<int MODE>
__global__ __launch_bounds__(256) void agg_csr(const float* __restrict__ xin,
    const int* __restrict__ row_ptr, const int* __restrict__ esrc,
    const float* __restrict__ eww, const float* __restrict__ out_n,
    const float* __restrict__ in_n, float* __restrict__ outp, int N){
  int node = (int)((blockIdx.x * (unsigned)blockDim.x + threadIdx.x) >> 6);
  int f = threadIdx.x & 63;
  if (node >= N) return;
  int e0 = row_ptr[node], e1 = row_ptr[node + 1];
  float acc = 0.f;
  #pragma unroll 2
  for (int e = e0; e < e1; ++e){
    int s = esrc[e];
    float w = eww[e];
    if (MODE == 1) w *= out_n[s];
    acc += xin[(size_t)s * 64 + f] * w;
  }
  acc *= in_n[node];
  if (MODE == 2) acc = leaky(acc);
  outp[(size_t)node * 64 + f] = acc;
}

// ---- h1 = leaky(agg1 @ W1)  [Nx64]@[64x128]  (in_n prefolded into agg1) ----
// 64 rows/block; thread = (colpair cp 0..63, rowgroup rg 0..3 x 16 rows)
__global__ __launch_bounds__(256) void gemm1_kernel(const float* __restrict__ agg,
    const float* __restrict__ W1, float* __restrict__ h1, int N){
  __shared__ float sW[64 * 128];        // 32 KB
  __shared__ float sIn[64][64];         // 16 KB
  int t = threadIdx.x;
  for (int i = t; i < 64 * 128 / 4; i += 256)
    ((float4*)sW)[i] = ((const float4*)W1)[i];
  int r0 = blockIdx.x * 64;
  for (int i = t; i < 64 * 16; i += 256){       // 64 rows x 16 float4
    int r = i >> 4, q = i & 15;
    int row = r0 + r;
    float4 v = make_float4(0.f, 0.f, 0.f, 0.f);
    if (row < N) v = ((const float4*)(agg + (size_t)row * 64))[q];
    ((float4*)&sIn[r][0])[q] = v;
  }
  __syncthreads();
  int cp = t & 63;          // cols 2cp, 2cp+1
  int rg = t >> 6;          // rows rg*16 .. rg*16+15  (wave-uniform -> broadcast reads)
  float2 acc[16];
  #pragma unroll
  for (int j = 0; j < 16; ++j) acc[j] = make_float2(0.f, 0.f);
  const float2* sW2 = (const float2*)sW;
  for (int k = 0; k < 64; k += 4){
    float2 w0 = sW2[(k + 0) * 64 + cp];
    float2 w1 = sW2[(k + 1) * 64 + cp];
    float2 w2 = sW2[(k + 2) * 64 + cp];
    float2 w3 = sW2[(k + 3) * 64 + cp];
    #pragma unroll
    for (int j = 0; j < 16; ++j){
      float4 a = *(const float4*)&sIn[rg * 16 + j][k];
      acc[j].x += a.x * w0.x + a.y * w1.x + a.z * w2.x + a.w * w3.x;
      acc[j].y += a.x * w0.y + a.y * w1.y + a.z * w2.y + a.w * w3.y;
    }
  }
  #pragma unroll
  for (int j = 0; j < 16; ++j){
    int row = r0 + rg * 16 + j;
    if (row < N){
      float2 o = make_float2(leaky(acc[j].x), leaky(acc[j].y));
      ((float2*)(h1 + (size_t)row * 128))[cp] = o;
    }
  }
}

// ---- per-feature column sums / sums-of-squares ----
template<int F>
__global__ void colstats_kernel(const float* __restrict__ h, int N,
                                float* __restrict__ sum, float* __restrict__ sumsq){
  int f = threadIdx.x;            // blockDim.x == F
  float s = 0.f, s2 = 0.f;
  for (int r = blockIdx.x; r < N; r += gridDim.x){
    float v = h[(size_t)r * F + f];
    s += v; s2 += v * v;
  }
  atomicAdd(&sum[f], s);
  atomicAdd(&sumsq[f], s2);
}

// ---- GraphNorm -> affine: a = g*rsqrt(var+eps), b = beta - a*alpha*mean ----
__global__ void finalize_norm(const float* __restrict__ sum, const float* __restrict__ sumsq,
                              const float* __restrict__ gamma, const float* __restrict__ beta,
                              const float* __restrict__ alpha,
                              float* __restrict__ a, float* __restrict__ b, int F, float invN){
  int f = threadIdx.x;
  if (f < F){
    float m = sum[f] * invN;
    float ex2 = sumsq[f] * invN;
    float al = alpha[f];
    float var = ex2 - m * m * al * (2.f - al);
    float av = gamma[f] * rsqrtf(var + EPS);
    a[f] = av;
    b[f] = beta[f] - av * al * m;
  }
}

// ---- z = ((a1*h1 + b1) * out_n) @ W2   [Nx128]@[128x64] ----
// 64 rows/block; thread = (colpair cp 0..31, rowgroup rg 0..7 x 8 rows)
__global__ __launch_bounds__(256) void gemm2_kernel(const float* __restrict__ h1,
    const float* __restrict__ out_n, const float* __restrict__ a1, const float* __restrict__ b1,
    const float* __restrict__ W2, float* __restrict__ z, int N){
  __shared__ float sW[128 * 64];        // 32 KB
  __shared__ float sIn[64][128];        // 32 KB
  int t = threadIdx.x;
  for (int i = t; i < 128 * 64 / 4; i += 256)
    ((float4*)sW)[i] = ((const float4*)W2)[i];
  int r0 = blockIdx.x * 64;
  for (int i = t; i < 64 * 32; i += 256){       // 64 rows x 32 float4
    int r = i >> 5, q = i & 31;
    int row = r0 + r;
    float4 v = make_float4(0.f, 0.f, 0.f, 0.f);
    if (row < N){
      float4 h  = ((const float4*)(h1 + (size_t)row * 128))[q];
      float4 av = ((const float4*)a1)[q];
      float4 bv = ((const float4*)b1)[q];
      float  on = out_n[row];
      v.x = (av.x * h.x + bv.x) * on;
      v.y = (av.y * h.y + bv.y) * on;
      v.z = (av.z * h.z + bv.z) * on;
      v.w = (av.w * h.w + bv.w) * on;
    }
    ((float4*)&sIn[r][0])[q] = v;
  }
  __syncthreads();
  int cp = t & 31;          // cols 2cp, 2cp+1
  int rg = t >> 5;          // rows rg*8 .. rg*8+7 (2 groups/wave -> 2-way broadcast, free)
  float2 acc[8];
  #pragma unroll
  for (int j = 0; j < 8; ++j) acc[j] = make_float2(0.f, 0.f);
  const float2* sW2 = (const float2*)sW;
  for (int k = 0; k < 128; k += 4){
    float2 w0 = sW2[(k + 0) * 32 + cp];
    float2 w1 = sW2[(k + 1) * 32 + cp];
    float2 w2 = sW2[(k + 2) * 32 + cp];
    float2 w3 = sW2[(k + 3) * 32 + cp];
    #pragma unroll
    for (int j = 0; j < 8; ++j){
      float4 a = *(const float4*)&sIn[rg * 8 + j][k];
      acc[j].x += a.x * w0.x + a.y * w1.x + a.z * w2.x + a.w * w3.x;
      acc[j].y += a.x * w0.y + a.y * w1.y + a.z * w2.y + a.w * w3.y;
    }
  }
  #pragma unroll
  for (int j = 0; j < 8; ++j){
    int row = r0 + rg * 8 + j;
    if (row < N) ((float2*)(z + (size_t)row * 64))[cp] = acc[j];
  }
}

// ---- stage2 epilogue: hv = leaky(agg2*in_n) already materialized by agg_csr<2>;
//      global per-feature stats + per-graph segment sums (graph_id sorted) ----
__global__ void post2_kernel(const float* __restrict__ hv, const int* __restrict__ gid,
                             int N, int chunk,
                             float* __restrict__ sum2, float* __restrict__ sumsq2,
                             float* __restrict__ segsum, float* __restrict__ cnt){
  int f = threadIdx.x;           // 64
  int r0 = blockIdx.x * chunk;
  int r1 = min(N, r0 + chunk);
  if (r0 >= r1) return;
  float s = 0.f, s2 = 0.f;
  int cur = gid[r0];
  float seg = 0.f;
  int run = 0;
  for (int r = r0; r < r1; ++r){
    int g = gid[r];
    if (g != cur){
      atomicAdd(&segsum[(size_t)cur * 64 + f], seg);
      if (f == 0) atomicAdd(&cnt[cur], (float)run);
      seg = 0.f; run = 0; cur = g;
    }
    float v = hv[(size_t)r * 64 + f];
    s += v; s2 += v * v;
    seg += v; ++run;
  }
  atomicAdd(&segsum[(size_t)cur * 64 + f], seg);
  if (f == 0) atomicAdd(&cnt[cur], (float)run);
  atomicAdd(&sum2[f], s);
  atomicAdd(&sumsq2[f], s2);
}

// ---- head: g = a2*segmean+b2 -> (L1,leaky,IN) -> (L2,leaky,IN) -> (L3,leaky,IN) -> Wc ----
__global__ void head_kernel(const float* __restrict__ segsum, const float* __restrict__ cnt,
                            const float* __restrict__ a2, const float* __restrict__ b2,
                            const float* __restrict__ L1, const float* __restrict__ L2,
                            const float* __restrict__ L3, const float* __restrict__ Wc,
                            float* __restrict__ out){
  __shared__ float bufA[64];
  __shared__ float bufB[32];
  __shared__ float bufC[8];
  int b = blockIdx.x;
  int j = threadIdx.x;          // 64
  float c = cnt[b];
  float g0 = (c > 0.f) ? (a2[j] * (segsum[(size_t)b * 64 + j] / c) + b2[j]) : 0.f;
  bufA[j] = g0;
  __syncthreads();
  // L1: 64 -> 32, leaky, instnorm over 32 lanes
  float y = 0.f;
  if (j < 32){
    float acc = 0.f;
    for (int f = 0; f < 64; ++f) acc += bufA[f] * L1[f * 32 + j];
    y = leaky(acc);
  }
  float m = y;
  for (int mask = 1; mask <= 16; mask <<= 1) m += __shfl_xor(m, mask);
  m *= (1.f / 32.f);
  float d = y - m;
  float v = d * d;
  for (int mask = 1; mask <= 16; mask <<= 1) v += __shfl_xor(v, mask);
  v *= (1.f / 32.f);
  float yn = d * rsqrtf(v + EPS);
  if (j < 32) bufB[j] = yn;
  __syncthreads();
  // L2: 32 -> 16, leaky, instnorm over 16 lanes
  y = 0.f;
  if (j < 16){
    float acc = 0.f;
    for (int f = 0; f < 32; ++f) acc += bufB[f] * L2[f * 16 + j];
    y = leaky(acc);
  }
  m = y;
  for (int mask = 1; mask <= 8; mask <<= 1) m += __shfl_xor(m, mask);
  m *= (1.f / 16.f);
  d = y - m; v = d * d;
  for (int mask = 1; mask <= 8; mask <<= 1) v += __shfl_xor(v, mask);
  v *= (1.f / 16.f);
  yn = d * rsqrtf(v + EPS);
  if (j < 16) bufA[j] = yn;     // reuse bufA
  __syncthreads();
  // L3: 16 -> 8, leaky, instnorm over 8 lanes
  y = 0.f;
  if (j < 8){
    float acc = 0.f;
    for (int f = 0; f < 16; ++f) acc += bufA[f] * L3[f * 8 + j];
    y = leaky(acc);
  }
  m = y;
  for (int mask = 1; mask <= 4; mask <<= 1) m += __shfl_xor(m, mask);
  m *= (1.f / 8.f);
  d = y - m; v = d * d;
  for (int mask = 1; mask <= 4; mask <<= 1) v += __shfl_xor(v, mask);
  v *= (1.f / 8.f);
  yn = d * rsqrtf(v + EPS);
  if (j < 8) bufC[j] = yn;
  __syncthreads();
  // classifier: 8 -> 16
  if (j < 16){
    float acc = 0.f;
    for (int f = 0; f < 8; ++f) acc += bufC[f] * Wc[f * 16 + j];
    out[(size_t)b * 16 + j] = acc;
  }
}

extern "C" void kernel_launch(void* const* d_in, const int* in_sizes, int n_in,
                              void* d_out, int out_size, void* d_ws, size_t ws_size,
                              hipStream_t stream){
  const float* x   = (const float*)d_in[0];
  const int*   src = (const int*)  d_in[1];
  const int*   dst = (const int*)  d_in[2];
  const float* ew  = (const float*)d_in[3];
  const int*   gid = (const int*)  d_in[4];
  const float* W1  = (const float*)d_in[5];
  const float* g1  = (const float*)d_in[6];
  const float* be1 = (const float*)d_in[7];
  const float* al1 = (const float*)d_in[8];
  const float* W2  = (const float*)d_in[9];
  const float* g2  = (const float*)d_in[10];
  const float* be2 = (const float*)d_in[11];
  const float* al2 = (const float*)d_in[12];
  const float* L1  = (const float*)d_in[13];
  const float* L2  = (const float*)d_in[14];
  const float* L3  = (const float*)d_in[15];
  const float* Wc  = (const float*)d_in[16];
  int N = in_sizes[0] / 64;
  int E = in_sizes[1];
  const int B = 50;
  int nb = (N + 255) / 256;     // scan blocks (196 at N=50000; supports <= 1024)

  // workspace layout: ints then floats (~46 MB total; buffers reused across stages)
  char* wsb = (char*)d_ws;
  size_t off = 0;
  int* iout    = (int*)(wsb + off); off += sizeof(int) * (size_t)N;      // -> cursor reuse
  int* iin     = (int*)(wsb + off); off += sizeof(int) * (size_t)N;
  int* row_ptr = (int*)(wsb + off); off += sizeof(int) * ((size_t)N + 1);
  int* bsum    = (int*)(wsb + off); off += sizeof(int) * 1024;
  int* boff    = (int*)(wsb + off); off += sizeof(int) * 1024;
  int* esrc    = (int*)(wsb + off); off += sizeof(int) * (size_t)E;
  float* eww   = (float*)(wsb + off); off += sizeof(float) * (size_t)E;
  float* out_n = (float*)(wsb + off); off += sizeof(float) * (size_t)N;
  float* in_n  = (float*)(wsb + off); off += sizeof(float) * (size_t)N;
  float* P     = (float*)(wsb + off); off += sizeof(float) * (size_t)N * 64;   // agg1, then z
  float* H     = (float*)(wsb + off); off += sizeof(float) * (size_t)N * 128;  // h1, then hv
  float* sum1  = (float*)(wsb + off); off += sizeof(float) * 128;
  float* sumsq1= (float*)(wsb + off); off += sizeof(float) * 128;
  float* a1    = (float*)(wsb + off); off += sizeof(float) * 128;
  float* b1    = (float*)(wsb + off); off += sizeof(float) * 128;
  float* sum2  = (float*)(wsb + off); off += sizeof(float) * 64;
  float* sumsq2= (float*)(wsb + off); off += sizeof(float) * 64;
  float* a2    = (float*)(wsb + off); off += sizeof(float) * 64;
  float* b2    = (float*)(wsb + off); off += sizeof(float) * 64;
  float* segsum= (float*)(wsb + off); off += sizeof(float) * (size_t)B * 64;
  float* cnt   = (float*)(wsb + off); off += sizeof(float) * B;
  int* cursor  = iout;  // iout dead after norm_kernel; scan_write initializes cursor

  // zero: degree histograms + stats block (ws is poisoned 0xAA every launch)
  hipMemsetAsync(iout, 0, sizeof(int) * (size_t)2 * N, stream);
  hipMemsetAsync(sum1, 0, sizeof(float) * (4 * 128 + 4 * 64 + (size_t)B * 64 + B), stream);

  // degrees + norms + CSR (built once, used by both convs)
  deg_kernel <<<(E + 255) / 256, 256, 0, stream>>>(src, dst, iout, iin, E);
  norm_kernel<<<(N + 255) / 256, 256, 0, stream>>>(iout, iin, out_n, in_n, N);
  scan_blocksum<<<nb, 256, 0, stream>>>(iin, bsum, N);
  scan_offsets <<<1, 1024, 0, stream>>>(bsum, boff, nb, row_ptr, N);
  scan_write   <<<nb, 256, 0, stream>>>(iin, boff, row_ptr, cursor, N);
  fill_kernel<<<(E + 255) / 256, 256, 0, stream>>>(src, dst, ew, cursor, esrc, eww, E);

  // conv1: atomic-free gather-reduce at F=64, then GEMM to 128 (+leaky)
  agg_csr<1><<<(N * 64 + 255) / 256, 256, 0, stream>>>(x, row_ptr, esrc, eww, out_n, in_n, P, N);
  gemm1_kernel<<<(N + 63) / 64, 256, 0, stream>>>(P, W1, H, N);
  colstats_kernel<128><<<256, 128, 0, stream>>>(H, N, sum1, sumsq1);
  finalize_norm<<<1, 128, 0, stream>>>(sum1, sumsq1, g1, be1, al1, a1, b1, 128, 1.f / (float)N);

  // conv2: GEMM to 64 first (norm1 + out_n folded), then gather-reduce (leaky+in_n folded)
  gemm2_kernel<<<(N + 63) / 64, 256, 0, stream>>>(H, out_n, a1, b1, W2, P, N);
  agg_csr<2><<<(N * 64 + 255) / 256, 256, 0, stream>>>(P, row_ptr, esrc, eww, nullptr, in_n, H, N);

  // stage2 epilogue: stats + segment sums over hv (=H)
  int chunk = (N + 1023) / 1024;
  post2_kernel<<<1024, 64, 0, stream>>>(H, gid, N, chunk, sum2, sumsq2, segsum, cnt);
  finalize_norm<<<1, 64, 0, stream>>>(sum2, sumsq2, g2, be2, al2, a2, b2, 64, 1.f / (float)N);

  head_kernel<<<B, 64, 0, stream>>>(segsum, cnt, a2, b2, L1, L2, L3, Wc, (float*)d_out);
}

// Round 15
// 463.930 us; speedup vs baseline: 1.6063x; 1.0621x over previous
//
#include <hip/hip_runtime.h>
#include <hip/hip_bf16.h>

// GNN pipeline: 2x GraphConv(norm=both, edge_weight) + LeakyReLU + GraphNorm,
// segment-mean readout, 3x (Linear+LeakyReLU+InstanceNorm), classifier.
// R3 -> R4:  atomic scatter -> CSR-by-dst gather (745->656us).
// R8 -> R9:  single-block scan -> parallel scan (656->566us).
// R12 -> R13: gemm register-blocked rewrite (566->493us).
// R14 -> R15: deg_kernel 66us = 1.6M device atomics x 32B write-through
//   (WRITE_SIZE 51MB @ 820GB/s). Removed ALL scattered device atomics from
//   CSR build: packed-16bit LDS histograms -> per-chunk partials (plain
//   writes) -> reduce -> cross-chunk exclusive scan -> rank-replay fill.
#define NEG_SLOPE 0.01f
#define EPS 1e-5f
#define NCHUNK 64
#define MAXW 25088   // packed u32 words; supports N <= 50176

__device__ __forceinline__ float leaky(float x){ return x > 0.f ? x : NEG_SLOPE * x; }

// ---- per-chunk packed-16bit histograms (LDS atomics only; plain global writes)
// blockIdx.x = c*2 + which; which 0 -> src (out-deg), 1 -> dst (in-deg)
__global__ __launch_bounds__(256) void hist_kernel(const int* __restrict__ src,
    const int* __restrict__ dst, int E, int ECH, int W,
    unsigned* __restrict__ partial_out, unsigned* __restrict__ partial_in){
  __shared__ unsigned sm[MAXW];
  int t = threadIdx.x;
  int c = blockIdx.x >> 1;
  int which = blockIdx.x & 1;
  for (int i = t; i < W; i += 256) sm[i] = 0u;
  __syncthreads();
  const int* ids = which ? dst : src;
  int e0 = c * ECH, e1 = min(E, e0 + ECH);
  for (int e = e0 + t; e < e1; e += 256){
    int v = ids[e];
    atomicAdd(&sm[v >> 1], 1u << ((v & 1) * 16));
  }
  __syncthreads();
  unsigned* outp = (which ? partial_in : partial_out) + (size_t)c * W;
  for (int i = t; i < W; i += 256) outp[i] = sm[i];
}

// ---- reduce partials -> out_n, in_n, iin (replaces deg+norm kernels) ----
__global__ void reduce_kernel(const unsigned* __restrict__ partial_out,
    const unsigned* __restrict__ partial_in, int W, int N,
    float* __restrict__ out_n, float* __restrict__ in_n, int* __restrict__ iin){
  int w = blockIdx.x * blockDim.x + threadIdx.x;
  if (w >= W) return;
  unsigned so = 0, si = 0;
  for (int c = 0; c < NCHUNK; ++c){
    so += partial_out[(size_t)c * W + w];
    si += partial_in[(size_t)c * W + w];
  }
  int n0 = 2 * w, n1 = 2 * w + 1;
  int o0 = so & 0xffff, o1 = so >> 16;
  int i0 = si & 0xffff, i1 = si >> 16;
  if (n0 < N){
    out_n[n0] = rsqrtf((float)(o0 > 0 ? o0 : 1));
    in_n[n0]  = rsqrtf((float)(i0 > 0 ? i0 : 1));
    iin[n0] = i0;
  }
  if (n1 < N){
    out_n[n1] = rsqrtf((float)(o1 > 0 ? o1 : 1));
    in_n[n1]  = rsqrtf((float)(i1 > 0 ? i1 : 1));
    iin[n1] = i1;
  }
}

// ---- in-place exclusive scan of dst-partials across chunks (per packed word)
// halves scan independently: per-node cumulative degree < 2^16 -> no carry.
__global__ void pexcl_kernel(unsigned* __restrict__ partial_in, int W){
  int w = blockIdx.x * blockDim.x + threadIdx.x;
  if (w >= W) return;
  unsigned run = 0;
  for (int c = 0; c < NCHUNK; ++c){
    unsigned v = partial_in[(size_t)c * W + w];
    partial_in[(size_t)c * W + w] = run;
    run += v;
  }
}

// ---- parallel exclusive scan of iin -> row_ptr (3 phases) ----
__global__ __launch_bounds__(256) void scan_blocksum(const int* __restrict__ iin,
                                                     int* __restrict__ bsum, int N){
  __shared__ int sm[256];
  int t = threadIdx.x;
  int i = blockIdx.x * 256 + t;
  sm[t] = (i < N) ? iin[i] : 0;
  __syncthreads();
  for (int off = 128; off > 0; off >>= 1){
    if (t < off) sm[t] += sm[t + off];
    __syncthreads();
  }
  if (t == 0) bsum[blockIdx.x] = sm[0];
}

__global__ __launch_bounds__(1024) void scan_offsets(const int* __restrict__ bsum,
    int* __restrict__ boff, int nb, int* __restrict__ row_ptr, int N){
  __shared__ int sm[1024];
  int t = threadIdx.x;
  sm[t] = (t < nb) ? bsum[t] : 0;
  __syncthreads();
  for (int off = 1; off < 1024; off <<= 1){
    int v = (t >= off) ? sm[t - off] : 0;
    __syncthreads();
    sm[t] += v;
    __syncthreads();
  }
  if (t < nb) boff[t] = (t == 0) ? 0 : sm[t - 1];
  if (t == 1023) row_ptr[N] = sm[1023];   // total edge count
}

__global__ __launch_bounds__(256) void scan_write(const int* __restrict__ iin,
    const int* __restrict__ boff, int* __restrict__ row_ptr, int N){
  __shared__ int sm[256];
  int t = threadIdx.x;
  int i = blockIdx.x * 256 + t;
  int v = (i < N) ? iin[i] : 0;
  sm[t] = v;
  __syncthreads();
  for (int off = 1; off < 256; off <<= 1){
    int u = (t >= off) ? sm[t - off] : 0;
    __syncthreads();
    sm[t] += u;
    __syncthreads();
  }
  if (i < N) row_ptr[i] = sm[t] - v + boff[blockIdx.x];
}

// ---- atomic-free CSR fill: rank via replayed LDS histogram ----
// pos = row_ptr[d] + (# same-d edges in earlier chunks) + (rank within chunk)
__global__ __launch_bounds__(256) void fill2_kernel(const int* __restrict__ src,
    const int* __restrict__ dst, const float* __restrict__ ew,
    const int* __restrict__ row_ptr, const unsigned* __restrict__ pexcl,
    int E, int ECH, int W, int* __restrict__ esrc, float* __restrict__ eww){
  __shared__ unsigned sm[MAXW];
  int t = threadIdx.x;
  int c = blockIdx.x;
  for (int i = t; i < W; i += 256) sm[i] = 0u;
  __syncthreads();
  const unsigned* pe = pexcl + (size_t)c * W;
  int e0 = c * ECH, e1 = min(E, e0 + ECH);
  for (int e = e0 + t; e < e1; e += 256){
    int d = dst[e];
    int sh = (d & 1) * 16;
    unsigned old = atomicAdd(&sm[d >> 1], 1u << sh);
    int rank = (int)((old >> sh) & 0xffffu);
    int base = (int)((pe[d >> 1] >> sh) & 0xffffu);
    int pos = row_ptr[d] + base + rank;
    esrc[pos] = src[e];
    eww[pos] = ew[e];
  }
}

// ---- atomic-free aggregation: one wave per node, lane = feature ----
template<int MODE>
__global__ __launch_bounds__(256) void agg_csr(const float* __restrict__ xin,
    const int* __restrict__ row_ptr, const int* __restrict__ esrc,
    const float* __restrict__ eww, const float* __restrict__ out_n,
    const float* __restrict__ in_n, float* __restrict__ outp, int N){
  int node = (int)((blockIdx.x * (unsigned)blockDim.x + threadIdx.x) >> 6);
  int f = threadIdx.x & 63;
  if (node >= N) return;
  int e0 = row_ptr[node], e1 = row_ptr[node + 1];
  float acc = 0.f;
  #pragma unroll 2
  for (int e = e0; e < e1; ++e){
    int s = esrc[e];
    float w = eww[e];
    if (MODE == 1) w *= out_n[s];
    acc += xin[(size_t)s * 64 + f] * w;
  }
  acc *= in_n[node];
  if (MODE == 2) acc = leaky(acc);
  outp[(size_t)node * 64 + f] = acc;
}

// ---- h1 = leaky(agg1 @ W1)  [Nx64]@[64x128] ----
__global__ __launch_bounds__(256) void gemm1_kernel(const float* __restrict__ agg,
    const float* __restrict__ W1, float* __restrict__ h1, int N){
  __shared__ float sW[64 * 128];        // 32 KB
  __shared__ float sIn[64][64];         // 16 KB
  int t = threadIdx.x;
  for (int i = t; i < 64 * 128 / 4; i += 256)
    ((float4*)sW)[i] = ((const float4*)W1)[i];
  int r0 = blockIdx.x * 64;
  for (int i = t; i < 64 * 16; i += 256){
    int r = i >> 4, q = i & 15;
    int row = r0 + r;
    float4 v = make_float4(0.f, 0.f, 0.f, 0.f);
    if (row < N) v = ((const float4*)(agg + (size_t)row * 64))[q];
    ((float4*)&sIn[r][0])[q] = v;
  }
  __syncthreads();
  int cp = t & 63;
  int rg = t >> 6;
  float2 acc[16];
  #pragma unroll
  for (int j = 0; j < 16; ++j) acc[j] = make_float2(0.f, 0.f);
  const float2* sW2 = (const float2*)sW;
  for (int k = 0; k < 64; k += 4){
    float2 w0 = sW2[(k + 0) * 64 + cp];
    float2 w1 = sW2[(k + 1) * 64 + cp];
    float2 w2 = sW2[(k + 2) * 64 + cp];
    float2 w3 = sW2[(k + 3) * 64 + cp];
    #pragma unroll
    for (int j = 0; j < 16; ++j){
      float4 a = *(const float4*)&sIn[rg * 16 + j][k];
      acc[j].x += a.x * w0.x + a.y * w1.x + a.z * w2.x + a.w * w3.x;
      acc[j].y += a.x * w0.y + a.y * w1.y + a.z * w2.y + a.w * w3.y;
    }
  }
  #pragma unroll
  for (int j = 0; j < 16; ++j){
    int row = r0 + rg * 16 + j;
    if (row < N){
      float2 o = make_float2(leaky(acc[j].x), leaky(acc[j].y));
      ((float2*)(h1 + (size_t)row * 128))[cp] = o;
    }
  }
}

// ---- per-feature column sums / sums-of-squares ----
template<int F>
__global__ void colstats_kernel(const float* __restrict__ h, int N,
                                float* __restrict__ sum, float* __restrict__ sumsq){
  int f = threadIdx.x;
  float s = 0.f, s2 = 0.f;
  for (int r = blockIdx.x; r < N; r += gridDim.x){
    float v = h[(size_t)r * F + f];
    s += v; s2 += v * v;
  }
  atomicAdd(&sum[f], s);
  atomicAdd(&sumsq[f], s2);
}

// ---- GraphNorm -> affine ----
__global__ void finalize_norm(const float* __restrict__ sum, const float* __restrict__ sumsq,
                              const float* __restrict__ gamma, const float* __restrict__ beta,
                              const float* __restrict__ alpha,
                              float* __restrict__ a, float* __restrict__ b, int F, float invN){
  int f = threadIdx.x;
  if (f < F){
    float m = sum[f] * invN;
    float ex2 = sumsq[f] * invN;
    float al = alpha[f];
    float var = ex2 - m * m * al * (2.f - al);
    float av = gamma[f] * rsqrtf(var + EPS);
    a[f] = av;
    b[f] = beta[f] - av * al * m;
  }
}

// ---- z = ((a1*h1 + b1) * out_n) @ W2   [Nx128]@[128x64] ----
__global__ __launch_bounds__(256) void gemm2_kernel(const float* __restrict__ h1,
    const float* __restrict__ out_n, const float* __restrict__ a1, const float* __restrict__ b1,
    const float* __restrict__ W2, float* __restrict__ z, int N){
  __shared__ float sW[128 * 64];        // 32 KB
  __shared__ float sIn[64][128];        // 32 KB
  int t = threadIdx.x;
  for (int i = t; i < 128 * 64 / 4; i += 256)
    ((float4*)sW)[i] = ((const float4*)W2)[i];
  int r0 = blockIdx.x * 64;
  for (int i = t; i < 64 * 32; i += 256){
    int r = i >> 5, q = i & 31;
    int row = r0 + r;
    float4 v = make_float4(0.f, 0.f, 0.f, 0.f);
    if (row < N){
      float4 h  = ((const float4*)(h1 + (size_t)row * 128))[q];
      float4 av = ((const float4*)a1)[q];
      float4 bv = ((const float4*)b1)[q];
      float  on = out_n[row];
      v.x = (av.x * h.x + bv.x) * on;
      v.y = (av.y * h.y + bv.y) * on;
      v.z = (av.z * h.z + bv.z) * on;
      v.w = (av.w * h.w + bv.w) * on;
    }
    ((float4*)&sIn[r][0])[q] = v;
  }
  __syncthreads();
  int cp = t & 31;
  int rg = t >> 5;
  float2 acc[8];
  #pragma unroll
  for (int j = 0; j < 8; ++j) acc[j] = make_float2(0.f, 0.f);
  const float2* sW2 = (const float2*)sW;
  for (int k = 0; k < 128; k += 4){
    float2 w0 = sW2[(k + 0) * 32 + cp];
    float2 w1 = sW2[(k + 1) * 32 + cp];
    float2 w2 = sW2[(k + 2) * 32 + cp];
    float2 w3 = sW2[(k + 3) * 32 + cp];
    #pragma unroll
    for (int j = 0; j < 8; ++j){
      float4 a = *(const float4*)&sIn[rg * 8 + j][k];
      acc[j].x += a.x * w0.x + a.y * w1.x + a.z * w2.x + a.w * w3.x;
      acc[j].y += a.x * w0.y + a.y * w1.y + a.z * w2.y + a.w * w3.y;
    }
  }
  #pragma unroll
  for (int j = 0; j < 8; ++j){
    int row = r0 + rg * 8 + j;
    if (row < N) ((float2*)(z + (size_t)row * 64))[cp] = acc[j];
  }
}

// ---- stage2 epilogue: global stats + per-graph segment sums ----
__global__ void post2_kernel(const float* __restrict__ hv, const int* __restrict__ gid,
                             int N, int chunk,
                             float* __restrict__ sum2, float* __restrict__ sumsq2,
                             float* __restrict__ segsum, float* __restrict__ cnt){
  int f = threadIdx.x;           // 64
  int r0 = blockIdx.x * chunk;
  int r1 = min(N, r0 + chunk);
  if (r0 >= r1) return;
  float s = 0.f, s2 = 0.f;
  int cur = gid[r0];
  float seg = 0.f;
  int run = 0;
  for (int r = r0; r < r1; ++r){
    int g = gid[r];
    if (g != cur){
      atomicAdd(&segsum[(size_t)cur * 64 + f], seg);
      if (f == 0) atomicAdd(&cnt[cur], (float)run);
      seg = 0.f; run = 0; cur = g;
    }
    float v = hv[(size_t)r * 64 + f];
    s += v; s2 += v * v;
    seg += v; ++run;
  }
  atomicAdd(&segsum[(size_t)cur * 64 + f], seg);
  if (f == 0) atomicAdd(&cnt[cur], (float)run);
  atomicAdd(&sum2[f], s);
  atomicAdd(&sumsq2[f], s2);
}

// ---- head ----
__global__ void head_kernel(const float* __restrict__ segsum, const float* __restrict__ cnt,
                            const float* __restrict__ a2, const float* __restrict__ b2,
                            const float* __restrict__ L1, const float* __restrict__ L2,
                            const float* __restrict__ L3, const float* __restrict__ Wc,
                            float* __restrict__ out){
  __shared__ float bufA[64];
  __shared__ float bufB[32];
  __shared__ float bufC[8];
  int b = blockIdx.x;
  int j = threadIdx.x;          // 64
  float c = cnt[b];
  float g0 = (c > 0.f) ? (a2[j] * (segsum[(size_t)b * 64 + j] / c) + b2[j]) : 0.f;
  bufA[j] = g0;
  __syncthreads();
  float y = 0.f;
  if (j < 32){
    float acc = 0.f;
    for (int f = 0; f < 64; ++f) acc += bufA[f] * L1[f * 32 + j];
    y = leaky(acc);
  }
  float m = y;
  for (int mask = 1; mask <= 16; mask <<= 1) m += __shfl_xor(m, mask);
  m *= (1.f / 32.f);
  float d = y - m;
  float v = d * d;
  for (int mask = 1; mask <= 16; mask <<= 1) v += __shfl_xor(v, mask);
  v *= (1.f / 32.f);
  float yn = d * rsqrtf(v + EPS);
  if (j < 32) bufB[j] = yn;
  __syncthreads();
  y = 0.f;
  if (j < 16){
    float acc = 0.f;
    for (int f = 0; f < 32; ++f) acc += bufB[f] * L2[f * 16 + j];
    y = leaky(acc);
  }
  m = y;
  for (int mask = 1; mask <= 8; mask <<= 1) m += __shfl_xor(m, mask);
  m *= (1.f / 16.f);
  d = y - m; v = d * d;
  for (int mask = 1; mask <= 8; mask <<= 1) v += __shfl_xor(v, mask);
  v *= (1.f / 16.f);
  yn = d * rsqrtf(v + EPS);
  if (j < 16) bufA[j] = yn;
  __syncthreads();
  y = 0.f;
  if (j < 8){
    float acc = 0.f;
    for (int f = 0; f < 16; ++f) acc += bufA[f] * L3[f * 8 + j];
    y = leaky(acc);
  }
  m = y;
  for (int mask = 1; mask <= 4; mask <<= 1) m += __shfl_xor(m, mask);
  m *= (1.f / 8.f);
  d = y - m; v = d * d;
  for (int mask = 1; mask <= 4; mask <<= 1) v += __shfl_xor(v, mask);
  v *= (1.f / 8.f);
  yn = d * rsqrtf(v + EPS);
  if (j < 8) bufC[j] = yn;
  __syncthreads();
  if (j < 16){
    float acc = 0.f;
    for (int f = 0; f < 8; ++f) acc += bufC[f] * Wc[f * 16 + j];
    out[(size_t)b * 16 + j] = acc;
  }
}

extern "C" void kernel_launch(void* const* d_in, const int* in_sizes, int n_in,
                              void* d_out, int out_size, void* d_ws, size_t ws_size,
                              hipStream_t stream){
  const float* x   = (const float*)d_in[0];
  const int*   src = (const int*)  d_in[1];
  const int*   dst = (const int*)  d_in[2];
  const float* ew  = (const float*)d_in[3];
  const int*   gid = (const int*)  d_in[4];
  const float* W1  = (const float*)d_in[5];
  const float* g1  = (const float*)d_in[6];
  const float* be1 = (const float*)d_in[7];
  const float* al1 = (const float*)d_in[8];
  const float* W2  = (const float*)d_in[9];
  const float* g2  = (const float*)d_in[10];
  const float* be2 = (const float*)d_in[11];
  const float* al2 = (const float*)d_in[12];
  const float* L1  = (const float*)d_in[13];
  const float* L2  = (const float*)d_in[14];
  const float* L3  = (const float*)d_in[15];
  const float* Wc  = (const float*)d_in[16];
  int N = in_sizes[0] / 64;
  int E = in_sizes[1];
  const int B = 50;
  int nb = (N + 255) / 256;
  int W = (N + 1) / 2;                    // packed words (25000 at N=50000)
  int ECH = (E + NCHUNK - 1) / NCHUNK;    // edges per chunk

  // workspace layout (~46 MB; partials overlay H which is dead until gemm1)
  char* wsb = (char*)d_ws;
  size_t off = 0;
  int* iin     = (int*)(wsb + off); off += sizeof(int) * (size_t)N;
  int* row_ptr = (int*)(wsb + off); off += sizeof(int) * ((size_t)N + 1);
  int* bsum    = (int*)(wsb + off); off += sizeof(int) * 1024;
  int* boff    = (int*)(wsb + off); off += sizeof(int) * 1024;
  int* esrc    = (int*)(wsb + off); off += sizeof(int) * (size_t)E;
  float* eww   = (float*)(wsb + off); off += sizeof(float) * (size_t)E;
  float* out_n = (float*)(wsb + off); off += sizeof(float) * (size_t)N;
  float* in_n  = (float*)(wsb + off); off += sizeof(float) * (size_t)N;
  float* P     = (float*)(wsb + off); off += sizeof(float) * (size_t)N * 64;   // agg1, then z
  float* H     = (float*)(wsb + off); off += sizeof(float) * (size_t)N * 128;  // h1, then hv
  float* sum1  = (float*)(wsb + off); off += sizeof(float) * 128;
  float* sumsq1= (float*)(wsb + off); off += sizeof(float) * 128;
  float* a1    = (float*)(wsb + off); off += sizeof(float) * 128;
  float* b1    = (float*)(wsb + off); off += sizeof(float) * 128;
  float* sum2  = (float*)(wsb + off); off += sizeof(float) * 64;
  float* sumsq2= (float*)(wsb + off); off += sizeof(float) * 64;
  float* a2    = (float*)(wsb + off); off += sizeof(float) * 64;
  float* b2    = (float*)(wsb + off); off += sizeof(float) * 64;
  float* segsum= (float*)(wsb + off); off += sizeof(float) * (size_t)B * 64;
  float* cnt   = (float*)(wsb + off); off += sizeof(float) * B;
  // histogram partials overlay H (H: 25.6MB >= 2 * NCHUNK * W * 4B = 12.8MB);
  // consumed by reduce/pexcl/fill2, all of which complete before gemm1 writes H.
  unsigned* partial_out = (unsigned*)H;
  unsigned* partial_in  = partial_out + (size_t)NCHUNK * W;

  // zero stats block only (histogram path fully overwrites its buffers)
  hipMemsetAsync(sum1, 0, sizeof(float) * (4 * 128 + 4 * 64 + (size_t)B * 64 + B), stream);

  // CSR build: no scattered device atomics anywhere
  hist_kernel <<<NCHUNK * 2, 256, 0, stream>>>(src, dst, E, ECH, W, partial_out, partial_in);
  reduce_kernel<<<(W + 255) / 256, 256, 0, stream>>>(partial_out, partial_in, W, N, out_n, in_n, iin);
  scan_blocksum<<<nb, 256, 0, stream>>>(iin, bsum, N);
  scan_offsets <<<1, 1024, 0, stream>>>(bsum, boff, nb, row_ptr, N);
  scan_write   <<<nb, 256, 0, stream>>>(iin, boff, row_ptr, N);
  pexcl_kernel <<<(W + 255) / 256, 256, 0, stream>>>(partial_in, W);
  fill2_kernel <<<NCHUNK, 256, 0, stream>>>(src, dst, ew, row_ptr, partial_in, E, ECH, W, esrc, eww);

  // conv1: gather-reduce at F=64, then GEMM to 128 (+leaky)
  agg_csr<1><<<(N * 64 + 255) / 256, 256, 0, stream>>>(x, row_ptr, esrc, eww, out_n, in_n, P, N);
  gemm1_kernel<<<(N + 63) / 64, 256, 0, stream>>>(P, W1, H, N);
  colstats_kernel<128><<<256, 128, 0, stream>>>(H, N, sum1, sumsq1);
  finalize_norm<<<1, 128, 0, stream>>>(sum1, sumsq1, g1, be1, al1, a1, b1, 128, 1.f / (float)N);

  // conv2: GEMM to 64 first (norm1 + out_n folded), then gather-reduce
  gemm2_kernel<<<(N + 63) / 64, 256, 0, stream>>>(H, out_n, a1, b1, W2, P, N);
  agg_csr<2><<<(N * 64 + 255) / 256, 256, 0, stream>>>(P, row_ptr, esrc, eww, nullptr, in_n, H, N);

  // stage2 epilogue: stats + segment sums over hv (=H)
  int chunk = (N + 1023) / 1024;
  post2_kernel<<<1024, 64, 0, stream>>>(H, gid, N, chunk, sum2, sumsq2, segsum, cnt);
  finalize_norm<<<1, 64, 0, stream>>>(sum2, sumsq2, g2, be2, al2, a2, b2, 64, 1.f / (float)N);

  head_kernel<<<B, 64, 0, stream>>>(segsum, cnt, a2, b2, L1, L2, L3, Wc, (float*)d_out);
}

// Round 16
// 433.333 us; speedup vs baseline: 1.7198x; 1.0706x over previous
//
#include <hip/hip_runtime.h>
#include <hip/hip_bf16.h>

// GNN pipeline: 2x GraphConv(norm=both, edge_weight) + LeakyReLU + GraphNorm,
// segment-mean readout, 3x (Linear+LeakyReLU+InstanceNorm), classifier.
// R3 -> R4:  atomic scatter -> CSR-by-dst gather (745->656us).
// R8 -> R9:  single-block scan -> parallel scan (656->566us).
// R12 -> R13: gemm register-blocked rewrite (566->493us).
// R14 -> R15: atomic-free CSR build via LDS histograms (493->464us).
// R15 -> R16: fill2 was 80us @ 2.6% occupancy (64 blocks x 4 waves,
//   latency-starved) + 60MB scatter write-through (2 arrays). Fix:
//   1024-thread blocks (4x waves) + packed int2{src,ew} single 8B store.
#define NEG_SLOPE 0.01f
#define EPS 1e-5f
#define NCHUNK 64
#define MAXW 25088   // packed u32 words; supports N <= 50176

__device__ __forceinline__ float leaky(float x){ return x > 0.f ? x : NEG_SLOPE * x; }

// ---- per-chunk packed-16bit histograms (LDS atomics only; plain global writes)
// blockIdx.x = c*2 + which; which 0 -> src (out-deg), 1 -> dst (in-deg)
__global__ __launch_bounds__(1024) void hist_kernel(const int* __restrict__ src,
    const int* __restrict__ dst, int E, int ECH, int W,
    unsigned* __restrict__ partial_out, unsigned* __restrict__ partial_in){
  __shared__ unsigned sm[MAXW];
  int t = threadIdx.x;
  int c = blockIdx.x >> 1;
  int which = blockIdx.x & 1;
  for (int i = t; i < W; i += 1024) sm[i] = 0u;
  __syncthreads();
  const int* ids = which ? dst : src;
  int e0 = c * ECH, e1 = min(E, e0 + ECH);
  for (int e = e0 + t; e < e1; e += 1024){
    int v = ids[e];
    atomicAdd(&sm[v >> 1], 1u << ((v & 1) * 16));
  }
  __syncthreads();
  unsigned* outp = (which ? partial_in : partial_out) + (size_t)c * W;
  for (int i = t; i < W; i += 1024) outp[i] = sm[i];
}

// ---- reduce partials -> out_n, in_n, iin ----
__global__ void reduce_kernel(const unsigned* __restrict__ partial_out,
    const unsigned* __restrict__ partial_in, int W, int N,
    float* __restrict__ out_n, float* __restrict__ in_n, int* __restrict__ iin){
  int w = blockIdx.x * blockDim.x + threadIdx.x;
  if (w >= W) return;
  unsigned so = 0, si = 0;
  for (int c = 0; c < NCHUNK; ++c){
    so += partial_out[(size_t)c * W + w];
    si += partial_in[(size_t)c * W + w];
  }
  int n0 = 2 * w, n1 = 2 * w + 1;
  int o0 = so & 0xffff, o1 = so >> 16;
  int i0 = si & 0xffff, i1 = si >> 16;
  if (n0 < N){
    out_n[n0] = rsqrtf((float)(o0 > 0 ? o0 : 1));
    in_n[n0]  = rsqrtf((float)(i0 > 0 ? i0 : 1));
    iin[n0] = i0;
  }
  if (n1 < N){
    out_n[n1] = rsqrtf((float)(o1 > 0 ? o1 : 1));
    in_n[n1]  = rsqrtf((float)(i1 > 0 ? i1 : 1));
    iin[n1] = i1;
  }
}

// ---- in-place exclusive scan of dst-partials across chunks (per packed word)
__global__ void pexcl_kernel(unsigned* __restrict__ partial_in, int W){
  int w = blockIdx.x * blockDim.x + threadIdx.x;
  if (w >= W) return;
  unsigned run = 0;
  for (int c = 0; c < NCHUNK; ++c){
    unsigned v = partial_in[(size_t)c * W + w];
    partial_in[(size_t)c * W + w] = run;
    run += v;
  }
}

// ---- parallel exclusive scan of iin -> row_ptr (3 phases) ----
__global__ __launch_bounds__(256) void scan_blocksum(const int* __restrict__ iin,
                                                     int* __restrict__ bsum, int N){
  __shared__ int sm[256];
  int t = threadIdx.x;
  int i = blockIdx.x * 256 + t;
  sm[t] = (i < N) ? iin[i] : 0;
  __syncthreads();
  for (int off = 128; off > 0; off >>= 1){
    if (t < off) sm[t] += sm[t + off];
    __syncthreads();
  }
  if (t == 0) bsum[blockIdx.x] = sm[0];
}

__global__ __launch_bounds__(1024) void scan_offsets(const int* __restrict__ bsum,
    int* __restrict__ boff, int nb, int* __restrict__ row_ptr, int N){
  __shared__ int sm[1024];
  int t = threadIdx.x;
  sm[t] = (t < nb) ? bsum[t] : 0;
  __syncthreads();
  for (int off = 1; off < 1024; off <<= 1){
    int v = (t >= off) ? sm[t - off] : 0;
    __syncthreads();
    sm[t] += v;
    __syncthreads();
  }
  if (t < nb) boff[t] = (t == 0) ? 0 : sm[t - 1];
  if (t == 1023) row_ptr[N] = sm[1023];   // total edge count
}

__global__ __launch_bounds__(256) void scan_write(const int* __restrict__ iin,
    const int* __restrict__ boff, int* __restrict__ row_ptr, int N){
  __shared__ int sm[256];
  int t = threadIdx.x;
  int i = blockIdx.x * 256 + t;
  int v = (i < N) ? iin[i] : 0;
  sm[t] = v;
  __syncthreads();
  for (int off = 1; off < 256; off <<= 1){
    int u = (t >= off) ? sm[t - off] : 0;
    __syncthreads();
    sm[t] += u;
    __syncthreads();
  }
  if (i < N) row_ptr[i] = sm[t] - v + boff[blockIdx.x];
}

// ---- atomic-free CSR fill: rank via replayed LDS histogram; packed 8B store
__global__ __launch_bounds__(1024) void fill2_kernel(const int* __restrict__ src,
    const int* __restrict__ dst, const float* __restrict__ ew,
    const int* __restrict__ row_ptr, const unsigned* __restrict__ pexcl,
    int E, int ECH, int W, int2* __restrict__ epk){
  __shared__ unsigned sm[MAXW];
  int t = threadIdx.x;
  int c = blockIdx.x;
  for (int i = t; i < W; i += 1024) sm[i] = 0u;
  __syncthreads();
  const unsigned* pe = pexcl + (size_t)c * W;
  int e0 = c * ECH, e1 = min(E, e0 + ECH);
  for (int e = e0 + t; e < e1; e += 1024){
    int d = dst[e];
    int sh = (d & 1) * 16;
    unsigned old = atomicAdd(&sm[d >> 1], 1u << sh);
    int rank = (int)((old >> sh) & 0xffffu);
    int base = (int)((pe[d >> 1] >> sh) & 0xffffu);
    int pos = row_ptr[d] + base + rank;
    epk[pos] = make_int2(src[e], __float_as_int(ew[e]));
  }
}

// ---- atomic-free aggregation: one wave per node, lane = feature ----
template<int MODE>
__global__ __launch_bounds__(256) void agg_csr(const float* __restrict__ xin,
    const int* __restrict__ row_ptr, const int2* __restrict__ epk,
    const float* __restrict__ out_n,
    const float* __restrict__ in_n, float* __restrict__ outp, int N){
  int node = (int)((blockIdx.x * (unsigned)blockDim.x + threadIdx.x) >> 6);
  int f = threadIdx.x & 63;
  if (node >= N) return;
  int e0 = row_ptr[node], e1 = row_ptr[node + 1];
  float acc = 0.f;
  #pragma unroll 2
  for (int e = e0; e < e1; ++e){
    int2 p = epk[e];
    int s = p.x;
    float w = __int_as_float(p.y);
    if (MODE == 1) w *= out_n[s];
    acc += xin[(size_t)s * 64 + f] * w;
  }
  acc *= in_n[node];
  if (MODE == 2) acc = leaky(acc);
  outp[(size_t)node * 64 + f] = acc;
}

// ---- h1 = leaky(agg1 @ W1)  [Nx64]@[64x128] ----
__global__ __launch_bounds__(256) void gemm1_kernel(const float* __restrict__ agg,
    const float* __restrict__ W1, float* __restrict__ h1, int N){
  __shared__ float sW[64 * 128];        // 32 KB
  __shared__ float sIn[64][64];         // 16 KB
  int t = threadIdx.x;
  for (int i = t; i < 64 * 128 / 4; i += 256)
    ((float4*)sW)[i] = ((const float4*)W1)[i];
  int r0 = blockIdx.x * 64;
  for (int i = t; i < 64 * 16; i += 256){
    int r = i >> 4, q = i & 15;
    int row = r0 + r;
    float4 v = make_float4(0.f, 0.f, 0.f, 0.f);
    if (row < N) v = ((const float4*)(agg + (size_t)row * 64))[q];
    ((float4*)&sIn[r][0])[q] = v;
  }
  __syncthreads();
  int cp = t & 63;
  int rg = t >> 6;
  float2 acc[16];
  #pragma unroll
  for (int j = 0; j < 16; ++j) acc[j] = make_float2(0.f, 0.f);
  const float2* sW2 = (const float2*)sW;
  for (int k = 0; k < 64; k += 4){
    float2 w0 = sW2[(k + 0) * 64 + cp];
    float2 w1 = sW2[(k + 1) * 64 + cp];
    float2 w2 = sW2[(k + 2) * 64 + cp];
    float2 w3 = sW2[(k + 3) * 64 + cp];
    #pragma unroll
    for (int j = 0; j < 16; ++j){
      float4 a = *(const float4*)&sIn[rg * 16 + j][k];
      acc[j].x += a.x * w0.x + a.y * w1.x + a.z * w2.x + a.w * w3.x;
      acc[j].y += a.x * w0.y + a.y * w1.y + a.z * w2.y + a.w * w3.y;
    }
  }
  #pragma unroll
  for (int j = 0; j < 16; ++j){
    int row = r0 + rg * 16 + j;
    if (row < N){
      float2 o = make_float2(leaky(acc[j].x), leaky(acc[j].y));
      ((float2*)(h1 + (size_t)row * 128))[cp] = o;
    }
  }
}

// ---- per-feature column sums / sums-of-squares ----
template<int F>
__global__ void colstats_kernel(const float* __restrict__ h, int N,
                                float* __restrict__ sum, float* __restrict__ sumsq){
  int f = threadIdx.x;
  float s = 0.f, s2 = 0.f;
  for (int r = blockIdx.x; r < N; r += gridDim.x){
    float v = h[(size_t)r * F + f];
    s += v; s2 += v * v;
  }
  atomicAdd(&sum[f], s);
  atomicAdd(&sumsq[f], s2);
}

// ---- GraphNorm -> affine ----
__global__ void finalize_norm(const float* __restrict__ sum, const float* __restrict__ sumsq,
                              const float* __restrict__ gamma, const float* __restrict__ beta,
                              const float* __restrict__ alpha,
                              float* __restrict__ a, float* __restrict__ b, int F, float invN){
  int f = threadIdx.x;
  if (f < F){
    float m = sum[f] * invN;
    float ex2 = sumsq[f] * invN;
    float al = alpha[f];
    float var = ex2 - m * m * al * (2.f - al);
    float av = gamma[f] * rsqrtf(var + EPS);
    a[f] = av;
    b[f] = beta[f] - av * al * m;
  }
}

// ---- z = ((a1*h1 + b1) * out_n) @ W2   [Nx128]@[128x64] ----
__global__ __launch_bounds__(256) void gemm2_kernel(const float* __restrict__ h1,
    const float* __restrict__ out_n, const float* __restrict__ a1, const float* __restrict__ b1,
    const float* __restrict__ W2, float* __restrict__ z, int N){
  __shared__ float sW[128 * 64];        // 32 KB
  __shared__ float sIn[64][128];        // 32 KB
  int t = threadIdx.x;
  for (int i = t; i < 128 * 64 / 4; i += 256)
    ((float4*)sW)[i] = ((const float4*)W2)[i];
  int r0 = blockIdx.x * 64;
  for (int i = t; i < 64 * 32; i += 256){
    int r = i >> 5, q = i & 31;
    int row = r0 + r;
    float4 v = make_float4(0.f, 0.f, 0.f, 0.f);
    if (row < N){
      float4 h  = ((const float4*)(h1 + (size_t)row * 128))[q];
      float4 av = ((const float4*)a1)[q];
      float4 bv = ((const float4*)b1)[q];
      float  on = out_n[row];
      v.x = (av.x * h.x + bv.x) * on;
      v.y = (av.y * h.y + bv.y) * on;
      v.z = (av.z * h.z + bv.z) * on;
      v.w = (av.w * h.w + bv.w) * on;
    }
    ((float4*)&sIn[r][0])[q] = v;
  }
  __syncthreads();
  int cp = t & 31;
  int rg = t >> 5;
  float2 acc[8];
  #pragma unroll
  for (int j = 0; j < 8; ++j) acc[j] = make_float2(0.f, 0.f);
  const float2* sW2 = (const float2*)sW;
  for (int k = 0; k < 128; k += 4){
    float2 w0 = sW2[(k + 0) * 32 + cp];
    float2 w1 = sW2[(k + 1) * 32 + cp];
    float2 w2 = sW2[(k + 2) * 32 + cp];
    float2 w3 = sW2[(k + 3) * 32 + cp];
    #pragma unroll
    for (int j = 0; j < 8; ++j){
      float4 a = *(const float4*)&sIn[rg * 8 + j][k];
      acc[j].x += a.x * w0.x + a.y * w1.x + a.z * w2.x + a.w * w3.x;
      acc[j].y += a.x * w0.y + a.y * w1.y + a.z * w2.y + a.w * w3.y;
    }
  }
  #pragma unroll
  for (int j = 0; j < 8; ++j){
    int row = r0 + rg * 8 + j;
    if (row < N) ((float2*)(z + (size_t)row * 64))[cp] = acc[j];
  }
}

// ---- stage2 epilogue: global stats + per-graph segment sums ----
__global__ void post2_kernel(const float* __restrict__ hv, const int* __restrict__ gid,
                             int N, int chunk,
                             float* __restrict__ sum2, float* __restrict__ sumsq2,
                             float* __restrict__ segsum, float* __restrict__ cnt){
  int f = threadIdx.x;           // 64
  int r0 = blockIdx.x * chunk;
  int r1 = min(N, r0 + chunk);
  if (r0 >= r1) return;
  float s = 0.f, s2 = 0.f;
  int cur = gid[r0];
  float seg = 0.f;
  int run = 0;
  for (int r = r0; r < r1; ++r){
    int g = gid[r];
    if (g != cur){
      atomicAdd(&segsum[(size_t)cur * 64 + f], seg);
      if (f == 0) atomicAdd(&cnt[cur], (float)run);
      seg = 0.f; run = 0; cur = g;
    }
    float v = hv[(size_t)r * 64 + f];
    s += v; s2 += v * v;
    seg += v; ++run;
  }
  atomicAdd(&segsum[(size_t)cur * 64 + f], seg);
  if (f == 0) atomicAdd(&cnt[cur], (float)run);
  atomicAdd(&sum2[f], s);
  atomicAdd(&sumsq2[f], s2);
}

// ---- head ----
__global__ void head_kernel(const float* __restrict__ segsum, const float* __restrict__ cnt,
                            const float* __restrict__ a2, const float* __restrict__ b2,
                            const float* __restrict__ L1, const float* __restrict__ L2,
                            const float* __restrict__ L3, const float* __restrict__ Wc,
                            float* __restrict__ out){
  __shared__ float bufA[64];
  __shared__ float bufB[32];
  __shared__ float bufC[8];
  int b = blockIdx.x;
  int j = threadIdx.x;          // 64
  float c = cnt[b];
  float g0 = (c > 0.f) ? (a2[j] * (segsum[(size_t)b * 64 + j] / c) + b2[j]) : 0.f;
  bufA[j] = g0;
  __syncthreads();
  float y = 0.f;
  if (j < 32){
    float acc = 0.f;
    for (int f = 0; f < 64; ++f) acc += bufA[f] * L1[f * 32 + j];
    y = leaky(acc);
  }
  float m = y;
  for (int mask = 1; mask <= 16; mask <<= 1) m += __shfl_xor(m, mask);
  m *= (1.f / 32.f);
  float d = y - m;
  float v = d * d;
  for (int mask = 1; mask <= 16; mask <<= 1) v += __shfl_xor(v, mask);
  v *= (1.f / 32.f);
  float yn = d * rsqrtf(v + EPS);
  if (j < 32) bufB[j] = yn;
  __syncthreads();
  y = 0.f;
  if (j < 16){
    float acc = 0.f;
    for (int f = 0; f < 32; ++f) acc += bufB[f] * L2[f * 16 + j];
    y = leaky(acc);
  }
  m = y;
  for (int mask = 1; mask <= 8; mask <<= 1) m += __shfl_xor(m, mask);
  m *= (1.f / 16.f);
  d = y - m; v = d * d;
  for (int mask = 1; mask <= 8; mask <<= 1) v += __shfl_xor(v, mask);
  v *= (1.f / 16.f);
  yn = d * rsqrtf(v + EPS);
  if (j < 16) bufA[j] = yn;
  __syncthreads();
  y = 0.f;
  if (j < 8){
    float acc = 0.f;
    for (int f = 0; f < 16; ++f) acc += bufA[f] * L3[f * 8 + j];
    y = leaky(acc);
  }
  m = y;
  for (int mask = 1; mask <= 4; mask <<= 1) m += __shfl_xor(m, mask);
  m *= (1.f / 8.f);
  d = y - m; v = d * d;
  for (int mask = 1; mask <= 4; mask <<= 1) v += __shfl_xor(v, mask);
  v *= (1.f / 8.f);
  yn = d * rsqrtf(v + EPS);
  if (j < 8) bufC[j] = yn;
  __syncthreads();
  if (j < 16){
    float acc = 0.f;
    for (int f = 0; f < 8; ++f) acc += bufC[f] * Wc[f * 16 + j];
    out[(size_t)b * 16 + j] = acc;
  }
}

extern "C" void kernel_launch(void* const* d_in, const int* in_sizes, int n_in,
                              void* d_out, int out_size, void* d_ws, size_t ws_size,
                              hipStream_t stream){
  const float* x   = (const float*)d_in[0];
  const int*   src = (const int*)  d_in[1];
  const int*   dst = (const int*)  d_in[2];
  const float* ew  = (const float*)d_in[3];
  const int*   gid = (const int*)  d_in[4];
  const float* W1  = (const float*)d_in[5];
  const float* g1  = (const float*)d_in[6];
  const float* be1 = (const float*)d_in[7];
  const float* al1 = (const float*)d_in[8];
  const float* W2  = (const float*)d_in[9];
  const float* g2  = (const float*)d_in[10];
  const float* be2 = (const float*)d_in[11];
  const float* al2 = (const float*)d_in[12];
  const float* L1  = (const float*)d_in[13];
  const float* L2  = (const float*)d_in[14];
  const float* L3  = (const float*)d_in[15];
  const float* Wc  = (const float*)d_in[16];
  int N = in_sizes[0] / 64;
  int E = in_sizes[1];
  const int B = 50;
  int nb = (N + 255) / 256;
  int W = (N + 1) / 2;                    // packed words (25000 at N=50000)
  int ECH = (E + NCHUNK - 1) / NCHUNK;    // edges per chunk

  // workspace layout (~46 MB; partials overlay H which is dead until gemm1)
  char* wsb = (char*)d_ws;
  size_t off = 0;
  int* iin     = (int*)(wsb + off); off += sizeof(int) * (size_t)N;
  int* row_ptr = (int*)(wsb + off); off += sizeof(int) * ((size_t)N + 1);
  int* bsum    = (int*)(wsb + off); off += sizeof(int) * 1024;
  int* boff    = (int*)(wsb + off); off += sizeof(int) * 1024;
  off = (off + 15) & ~(size_t)15;         // 16B align for int2 array
  int2* epk    = (int2*)(wsb + off); off += sizeof(int2) * (size_t)E;
  float* out_n = (float*)(wsb + off); off += sizeof(float) * (size_t)N;
  float* in_n  = (float*)(wsb + off); off += sizeof(float) * (size_t)N;
  float* P     = (float*)(wsb + off); off += sizeof(float) * (size_t)N * 64;   // agg1, then z
  float* H     = (float*)(wsb + off); off += sizeof(float) * (size_t)N * 128;  // h1, then hv
  float* sum1  = (float*)(wsb + off); off += sizeof(float) * 128;
  float* sumsq1= (float*)(wsb + off); off += sizeof(float) * 128;
  float* a1    = (float*)(wsb + off); off += sizeof(float) * 128;
  float* b1    = (float*)(wsb + off); off += sizeof(float) * 128;
  float* sum2  = (float*)(wsb + off); off += sizeof(float) * 64;
  float* sumsq2= (float*)(wsb + off); off += sizeof(float) * 64;
  float* a2    = (float*)(wsb + off); off += sizeof(float) * 64;
  float* b2    = (float*)(wsb + off); off += sizeof(float) * 64;
  float* segsum= (float*)(wsb + off); off += sizeof(float) * (size_t)B * 64;
  float* cnt   = (float*)(wsb + off); off += sizeof(float) * B;
  // histogram partials overlay H (H: 25.6MB >= 2 * NCHUNK * W * 4B = 12.8MB);
  // consumed by reduce/pexcl/fill2, all before gemm1 writes H.
  unsigned* partial_out = (unsigned*)H;
  unsigned* partial_in  = partial_out + (size_t)NCHUNK * W;

  // zero stats block only (histogram path fully overwrites its buffers)
  hipMemsetAsync(sum1, 0, sizeof(float) * (4 * 128 + 4 * 64 + (size_t)B * 64 + B), stream);

  // CSR build: no scattered device atomics anywhere
  hist_kernel <<<NCHUNK * 2, 1024, 0, stream>>>(src, dst, E, ECH, W, partial_out, partial_in);
  reduce_kernel<<<(W + 255) / 256, 256, 0, stream>>>(partial_out, partial_in, W, N, out_n, in_n, iin);
  scan_blocksum<<<nb, 256, 0, stream>>>(iin, bsum, N);
  scan_offsets <<<1, 1024, 0, stream>>>(bsum, boff, nb, row_ptr, N);
  scan_write   <<<nb, 256, 0, stream>>>(iin, boff, row_ptr, N);
  pexcl_kernel <<<(W + 255) / 256, 256, 0, stream>>>(partial_in, W);
  fill2_kernel <<<NCHUNK, 1024, 0, stream>>>(src, dst, ew, row_ptr, partial_in, E, ECH, W, epk);

  // conv1: gather-reduce at F=64, then GEMM to 128 (+leaky)
  agg_csr<1><<<(N * 64 + 255) / 256, 256, 0, stream>>>(x, row_ptr, epk, out_n, in_n, P, N);
  gemm1_kernel<<<(N + 63) / 64, 256, 0, stream>>>(P, W1, H, N);
  colstats_kernel<128><<<256, 128, 0, stream>>>(H, N, sum1, sumsq1);
  finalize_norm<<<1, 128, 0, stream>>>(sum1, sumsq1, g1, be1, al1, a1, b1, 128, 1.f / (float)N);

  // conv2: GEMM to 64 first (norm1 + out_n folded), then gather-reduce
  gemm2_kernel<<<(N + 63) / 64, 256, 0, stream>>>(H, out_n, a1, b1, W2, P, N);
  agg_csr<2><<<(N * 64 + 255) / 256, 256, 0, stream>>>(P, row_ptr, epk, nullptr, in_n, H, N);

  // stage2 epilogue: stats + segment sums over hv (=H)
  int chunk = (N + 1023) / 1024;
  post2_kernel<<<1024, 64, 0, stream>>>(H, gid, N, chunk, sum2, sumsq2, segsum, cnt);
  finalize_norm<<<1, 64, 0, stream>>>(sum2, sumsq2, g2, be2, al2, a2, b2, 64, 1.f / (float)N);

  head_kernel<<<B, 64, 0, stream>>>(segsum, cnt, a2, b2, L1, L2, L3, Wc, (float*)d_out);
}